// Round 5
// baseline (243.655 us; speedup 1.0000x reference)
//
#include <hip/hip_runtime.h>
#include <hip/hip_bf16.h>

typedef __bf16 bf16x8 __attribute__((ext_vector_type(8)));
typedef __bf16 bf16x4v __attribute__((ext_vector_type(4)));
typedef float f32x4 __attribute__((ext_vector_type(4)));

#define DMODEL 2048
#define NH 16
#define HD 128
#define PLEN 512
#define QLEN 2048
#define KVLEN 2560

#define FENCE() asm volatile("" ::: "memory")
#define LGKM0() asm volatile("s_waitcnt lgkmcnt(0)" ::: "memory")

__device__ __forceinline__ void gload_lds16(const void* g, void* l) {
  __builtin_amdgcn_global_load_lds((const __attribute__((address_space(1))) void*)g,
                                   (__attribute__((address_space(3))) void*)l, 16, 0, 0);
}

// ---------------- conversion kernels ----------------

// f32 [2048][2048] row-major -> bf16 transposed [2048][2048]
__global__ __launch_bounds__(256) void k_transpose_bf16(const float* __restrict__ in,
                                                        __bf16* __restrict__ out) {
  __shared__ float tile[64][65];
  const int t = threadIdx.x;
  const int tx = t & 63, ty = t >> 6;
  const int r0 = blockIdx.y * 64, c0 = blockIdx.x * 64;
#pragma unroll
  for (int i = 0; i < 16; ++i) {
    int r = ty + i * 4;
    tile[r][tx] = in[(size_t)(r0 + r) * DMODEL + c0 + tx];
  }
  __syncthreads();
#pragma unroll
  for (int i = 0; i < 16; ++i) {
    int r = ty + i * 4;
    out[(size_t)(c0 + r) * DMODEL + r0 + tx] = (__bf16)tile[tx][r];
  }
}

__global__ __launch_bounds__(256) void k_f32_to_bf16(const float* __restrict__ in,
                                                     __bf16* __restrict__ out, int n4) {
  int i = blockIdx.x * blockDim.x + threadIdx.x;
  int stride = gridDim.x * blockDim.x;
  for (; i < n4; i += stride) {
    float4 v = ((const float4*)in)[i];
    bf16x4v o;
    o[0] = (__bf16)v.x; o[1] = (__bf16)v.y; o[2] = (__bf16)v.z; o[3] = (__bf16)v.w;
    ((bf16x4v*)out)[i] = o;
  }
}

// prefix_key/value f32 [512][16][128] -> K[h][p][hd], VT[h][hd][p]  (bf16)
__global__ __launch_bounds__(256) void k_prefix(const float* __restrict__ pk,
                                                const float* __restrict__ pv,
                                                __bf16* __restrict__ Kall,
                                                __bf16* __restrict__ VT) {
  int idx = blockIdx.x * 256 + threadIdx.x;  // 512*16*128 = 1048576 exact
  int hd = idx & 127;
  int h = (idx >> 7) & 15;
  int p = idx >> 11;
  Kall[(size_t)h * KVLEN * HD + (size_t)p * HD + hd] = (__bf16)pk[idx];
  VT[(size_t)h * HD * KVLEN + (size_t)hd * KVLEN + p] = (__bf16)pv[idx];
}

// ---------------- GEMM: C[128 x BN] = A[M,K] * BT[N,K]^T ----------------
// 3-buffer, depth-2 prefetch, counted vmcnt (never 0 in loop), raw barriers.
// 4 waves; wave (w>>1, w&1) owns a 64 x (BN/2) quadrant. BK=32.

template <int BN>
__device__ __forceinline__ void stage_tile(const __bf16* __restrict__ A,
                                           const __bf16* __restrict__ BT,
                                           char* AsmB, char* BsmB,
                                           int m0, int n0, int k0, int w, int l) {
#pragma unroll
  for (int i = 0; i < 2; ++i) {  // A: 128x32 bf16 = 8KB
    int base = i * 4096 + w * 1024;
    int o = base + l * 16;
    int row = o >> 6, col = (o & 63) >> 1;
    gload_lds16(A + (size_t)(m0 + row) * DMODEL + k0 + col, AsmB + base);
  }
  if constexpr (BN == 128) {
#pragma unroll
    for (int i = 0; i < 2; ++i) {
      int base = i * 4096 + w * 1024;
      int o = base + l * 16;
      int row = o >> 6, col = (o & 63) >> 1;
      gload_lds16(BT + (size_t)(n0 + row) * DMODEL + k0 + col, BsmB + base);
    }
  } else {  // BN==64: 4KB
    int base = w * 1024;
    int o = base + l * 16;
    int row = o >> 6, col = (o & 63) >> 1;
    gload_lds16(BT + (size_t)(n0 + row) * DMODEL + k0 + col, BsmB + base);
  }
}

template <int BN>
__device__ __forceinline__ void gemm_mainloop_db(const __bf16* __restrict__ A,
                                                 const __bf16* __restrict__ BT,
                                                 __bf16* Asm, __bf16* Bsm,  // [3][...]
                                                 int m0, int n0, int w, int l,
                                                 f32x4 (&acc)[4][BN / 32]) {
  constexpr int NI = BN / 32;
  constexpr int ABUF = 4096;           // elements per A buffer
  constexpr int BBUF = BN * 32;        // elements per B buffer
  const int lr = l & 15, lg = l >> 4;
  stage_tile<BN>(A, BT, (char*)Asm, (char*)Bsm, m0, n0, 0, w, l);
  stage_tile<BN>(A, BT, (char*)(Asm + ABUF), (char*)(Bsm + BBUF), m0, n0, 32, w, l);
  int cur = 0;
  for (int k0 = 0; k0 < DMODEL; k0 += 32) {
    int k2 = k0 + 64;
    if (k2 > DMODEL - 32) k2 = DMODEL - 32;  // dummy re-stage at tail (never read)
    int nxt = cur + 2; if (nxt >= 3) nxt -= 3;
    stage_tile<BN>(A, BT, (char*)(Asm + nxt * ABUF), (char*)(Bsm + nxt * BBUF),
                   m0, n0, k2, w, l);
    if constexpr (BN == 128) {
      asm volatile("s_waitcnt vmcnt(8)" ::: "memory");
    } else {
      asm volatile("s_waitcnt vmcnt(6)" ::: "memory");
    }
    FENCE(); __builtin_amdgcn_s_barrier(); FENCE();
    const __bf16* Ab = Asm + cur * ABUF;
    const __bf16* Bb = Bsm + cur * BBUF;
    bf16x8 af[4], bfv[NI];
#pragma unroll
    for (int mi = 0; mi < 4; ++mi)
      af[mi] = *(const bf16x8*)(Ab + ((w >> 1) * 64 + mi * 16 + lr) * 32 + lg * 8);
#pragma unroll
    for (int ni = 0; ni < NI; ++ni)
      bfv[ni] = *(const bf16x8*)(Bb + ((w & 1) * (BN / 2) + ni * 16 + lr) * 32 + lg * 8);
    __builtin_amdgcn_s_setprio(1);
#pragma unroll
    for (int mi = 0; mi < 4; ++mi)
#pragma unroll
      for (int ni = 0; ni < NI; ++ni)
        acc[mi][ni] = __builtin_amdgcn_mfma_f32_16x16x32_bf16(af[mi], bfv[ni], acc[mi][ni], 0, 0, 0);
    __builtin_amdgcn_s_setprio(0);
    LGKM0();
    FENCE(); __builtin_amdgcn_s_barrier(); FENCE();
    cur = cur + 1; if (cur >= 3) cur -= 3;
  }
}

// z=0: Q (scaled 1/sqrt(128)) -> Qs[h][q][hd]; z=1: K -> Kall[h][512+q][hd]; z=2: V -> VT[h][hd][512+q]
__global__ __launch_bounds__(256) void gemm_qkv(const __bf16* __restrict__ xb,
                                                const __bf16* __restrict__ WqT,
                                                const __bf16* __restrict__ WkT,
                                                const __bf16* __restrict__ WvT,
                                                const float* __restrict__ bq,
                                                const float* __restrict__ bk,
                                                const float* __restrict__ bv,
                                                __bf16* __restrict__ Qs,
                                                __bf16* __restrict__ Kall,
                                                __bf16* __restrict__ VT) {
  __shared__ __bf16 Asm[3][4096];
  __shared__ __bf16 Bsm[3][4096];
  const int t = threadIdx.x, w = t >> 6, l = t & 63;
  // XCD swizzle: 768 blocks, 96 per XCD
  const int id = blockIdx.x;
  const int id2 = (id & 7) * 96 + (id >> 3);
  const int z = id2 >> 8;
  const int rem = id2 & 255;
  const int m0 = (rem & 15) * 128, n0 = (rem >> 4) * 128;
  const __bf16* BT = (z == 0) ? WqT : ((z == 1) ? WkT : WvT);
  const float* bias = (z == 0) ? bq : ((z == 1) ? bk : bv);
  f32x4 acc[4][4];
#pragma unroll
  for (int mi = 0; mi < 4; ++mi)
#pragma unroll
    for (int ni = 0; ni < 4; ++ni) acc[mi][ni] = (f32x4){0.f, 0.f, 0.f, 0.f};
  gemm_mainloop_db<128>(xb, BT, &Asm[0][0], &Bsm[0][0], m0, n0, w, l, acc);
  const int lr = l & 15, lg = l >> 4;
#pragma unroll
  for (int mi = 0; mi < 4; ++mi)
#pragma unroll
    for (int ni = 0; ni < 4; ++ni)
#pragma unroll
      for (int r = 0; r < 4; ++r) {
        int row = m0 + (w >> 1) * 64 + mi * 16 + lg * 4 + r;
        int col = n0 + (w & 1) * 64 + ni * 16 + lr;
        float v = acc[mi][ni][r] + bias[col];
        int hh = col >> 7, hd = col & 127;
        if (z == 0) {
          Qs[(size_t)hh * QLEN * HD + (size_t)row * HD + hd] = (__bf16)(v * 0.08838834764831845f);
        } else if (z == 1) {
          Kall[(size_t)hh * KVLEN * HD + (size_t)(PLEN + row) * HD + hd] = (__bf16)v;
        } else {
          VT[(size_t)hh * HD * KVLEN + (size_t)hd * KVLEN + (PLEN + row)] = (__bf16)v;
        }
      }
}

// final: out[q][d] = O[q][:] . WoT[d][:] + bout[d]  (f32 out).  128x64 tiles, 512 blocks.
__global__ __launch_bounds__(256) void gemm_out(const __bf16* __restrict__ Ob,
                                                const __bf16* __restrict__ WoT,
                                                const float* __restrict__ bout,
                                                float* __restrict__ out) {
  __shared__ __bf16 Asm[3][4096];
  __shared__ __bf16 Bsm[3][2048];
  const int t = threadIdx.x, w = t >> 6, l = t & 63;
  const int id = blockIdx.x;
  const int id2 = (id & 7) * 64 + (id >> 3);
  const int m0 = (id2 & 15) * 128, n0 = (id2 >> 4) * 64;
  f32x4 acc[4][2];
#pragma unroll
  for (int mi = 0; mi < 4; ++mi)
#pragma unroll
    for (int ni = 0; ni < 2; ++ni) acc[mi][ni] = (f32x4){0.f, 0.f, 0.f, 0.f};
  gemm_mainloop_db<64>(Ob, WoT, &Asm[0][0], &Bsm[0][0], m0, n0, w, l, acc);
  const int lr = l & 15, lg = l >> 4;
#pragma unroll
  for (int mi = 0; mi < 4; ++mi)
#pragma unroll
    for (int ni = 0; ni < 2; ++ni)
#pragma unroll
      for (int r = 0; r < 4; ++r) {
        int row = m0 + (w >> 1) * 64 + mi * 16 + lg * 4 + r;
        int col = n0 + (w & 1) * 32 + ni * 16 + lr;
        out[(size_t)row * DMODEL + col] = acc[mi][ni][r] + bout[col];
      }
}

// ---------------- attention ----------------
// Flat grid 512, XCD-swizzled: id2=(id&7)*64+(id>>3); h=id2>>5; bx=id2&31;
// qt=(h&1)?31-bx:bx  (per-CU tile count constant under round-robin-within-XCD).
// Unified tile stream: prefix (keys 0..511) and suffix are CONTIGUOUS in Kall/VT,
// so tile i stages keys [i*32, i*32+32) for all i; only accumulator/mask switch at i=16.
// 3-buffer, depth-2 prefetch, counted vmcnt(8) (never 0), raw barriers.
// Fixed-max softmax exp(S-16): |logit| <= ~12 by Cauchy-Schwarz (q pre-scaled).
__global__ __launch_bounds__(256, 2) void k_attn(const __bf16* __restrict__ Qs,
                                                 const __bf16* __restrict__ Kall,
                                                 const __bf16* __restrict__ VT,
                                                 const float* __restrict__ gate,
                                                 __bf16* __restrict__ Ob) {
  __shared__ __bf16 Ksm[3][4096];   // [buf][32 kv][128 hd] (xor-swizzled)
  __shared__ __bf16 Vsm[3][4096];   // [buf][128 hd][32 kv] (xor-swizzled)
  __shared__ __bf16 Pl[4][16 * 40]; // per-wave P tile, stride 40 (bank-spread)
  const int id2 = (blockIdx.x & 7) * 64 + (blockIdx.x >> 3);
  const int h = id2 >> 5;
  const int bx = id2 & 31;
  const int qt = (h & 1) ? (31 - bx) : bx;
  const int t = threadIdx.x, w = t >> 6, l = t & 63;
  const int lr = l & 15, lg = l >> 4;
  const int q0 = qt * 64 + w * 16;
  const __bf16* Qh = Qs + (size_t)h * QLEN * HD;
  const char* Khb = (const char*)(Kall + (size_t)h * KVLEN * HD);
  const char* Vhb = (const char*)(VT + (size_t)h * HD * KVLEN);
  __bf16* Pw = &Pl[w][0];

  bf16x8 qf[4];
#pragma unroll
  for (int c = 0; c < 4; ++c)
    qf[c] = *(const bf16x8*)(Qh + (size_t)(q0 + lr) * HD + c * 32 + lg * 8);

  f32x4 acc1[8], acc2[8];
  float ss1[4], ss2[4];
#pragma unroll
  for (int c = 0; c < 8; ++c) {
    acc1[c] = (f32x4){0.f, 0.f, 0.f, 0.f};
    acc2[c] = (f32x4){0.f, 0.f, 0.f, 0.f};
  }
#pragma unroll
  for (int r = 0; r < 4; ++r) { ss1[r] = 0.f; ss2[r] = 0.f; }

  // stage 32-key tile (keys kb..kb+31) into buffer `buf`
  auto STAGE = [&](int buf, int kb) {
#pragma unroll
    for (int i = 0; i < 2; ++i) {  // K: 8KB, rows contiguous in global
      int o = (i * 256 + w * 64 + l) * 16;
      int po = o ^ (((o >> 8) & 7) << 4);
      gload_lds16(Khb + (size_t)kb * 256 + po, (char*)&Ksm[buf][0] + i * 4096 + w * 1024);
    }
#pragma unroll
    for (int i = 0; i < 2; ++i) {  // V: 8KB, rows strided KVLEN*2 in global VT
      int o = (i * 256 + w * 64 + l) * 16;
      int po = o ^ (((o >> 7) & 7) << 4);
      int row = po >> 6, colb = po & 63;
      gload_lds16(Vhb + (size_t)row * (KVLEN * 2) + (size_t)kb * 2 + colb,
                  (char*)&Vsm[buf][0] + i * 4096 + w * 1024);
    }
  };

  // compute one staged tile into (ACC, SS); mrel = suffix-relative key base for masking
  auto COMPUTE = [&](int buf, int mrel, bool domask, f32x4 (&ACC)[8], float (&SS)[4]) {
    const char* Kb = (const char*)&Ksm[buf][0];
    const char* Vb = (const char*)&Vsm[buf][0];
    f32x4 st0 = {0.f, 0.f, 0.f, 0.f}, st1 = {0.f, 0.f, 0.f, 0.f};
    __builtin_amdgcn_s_setprio(1);
#pragma unroll
    for (int c = 0; c < 4; ++c) {
      int o0 = lr * 256 + c * 64 + lg * 16;        o0 ^= ((o0 >> 8) & 7) << 4;
      int o1 = (16 + lr) * 256 + c * 64 + lg * 16; o1 ^= ((o1 >> 8) & 7) << 4;
      bf16x8 kf0 = *(const bf16x8*)(Kb + o0);
      bf16x8 kf1 = *(const bf16x8*)(Kb + o1);
      st0 = __builtin_amdgcn_mfma_f32_16x16x32_bf16(qf[c], kf0, st0, 0, 0, 0);
      st1 = __builtin_amdgcn_mfma_f32_16x16x32_bf16(qf[c], kf1, st1, 0, 0, 0);
    }
    __builtin_amdgcn_s_setprio(0);
#pragma unroll
    for (int r = 0; r < 4; ++r) {
      if (domask) {
        int qq = q0 + lg * 4 + r;
        if (mrel + lr > qq) st0[r] = -1e30f;
        if (mrel + 16 + lr > qq) st1[r] = -1e30f;
      }
      float p0 = __expf(st0[r] - 16.0f);
      float p1 = __expf(st1[r] - 16.0f);
      SS[r] += p0 + p1;
      Pw[(lg * 4 + r) * 40 + lr] = (__bf16)p0;
      Pw[(lg * 4 + r) * 40 + 16 + lr] = (__bf16)p1;
    }
    bf16x8 pf = *(const bf16x8*)(Pw + lr * 40 + lg * 8);
    __builtin_amdgcn_s_setprio(1);
#pragma unroll
    for (int c = 0; c < 8; ++c) {
      int o = (c * 16 + lr) * 64 + lg * 16; o ^= ((o >> 7) & 7) << 4;
      bf16x8 vf = *(const bf16x8*)(Vb + o);
      ACC[c] = __builtin_amdgcn_mfma_f32_16x16x32_bf16(pf, vf, ACC[c], 0, 0, 0);
    }
    __builtin_amdgcn_s_setprio(0);
  };

  // ---- unified pipelined tile loop: tiles 0..NT-1, tile i = keys [i*32, i*32+32) ----
  const int NT = 16 + 2 * qt + 2;       // 16 prefix + block-uniform suffix count
  STAGE(0, 0);
  STAGE(1, 32);
  int cur = 0;
#pragma unroll 1
  for (int i = 0; i < NT; ++i) {
    int it = i + 2; if (it > NT - 1) it = NT - 1;   // dummy re-stage at tail
    int nxt = cur + 2; if (nxt >= 3) nxt -= 3;
    STAGE(nxt, it * 32);
    asm volatile("s_waitcnt vmcnt(8)" ::: "memory");
    FENCE(); __builtin_amdgcn_s_barrier(); FENCE();
    if (i < 16) {
      COMPUTE(cur, 0, false, acc1, ss1);
    } else {
      const int mrel = (i - 16) * 32;
      COMPUTE(cur, mrel, mrel + 31 > q0, acc2, ss2);
    }
    LGKM0();
    FENCE(); __builtin_amdgcn_s_barrier(); FENCE();
    cur = cur + 1; if (cur >= 3) cur -= 3;
  }

  // ---- epilogue: Ob = gate*acc1/s1 + acc2/s2 ----
  const float g = gate[h];
#pragma unroll
  for (int r = 0; r < 4; ++r) {
    float s1 = ss1[r];
    s1 += __shfl_xor(s1, 1); s1 += __shfl_xor(s1, 2);
    s1 += __shfl_xor(s1, 4); s1 += __shfl_xor(s1, 8);
    float s2 = ss2[r];
    s2 += __shfl_xor(s2, 1); s2 += __shfl_xor(s2, 2);
    s2 += __shfl_xor(s2, 4); s2 += __shfl_xor(s2, 8);
    const float f1 = g / s1;
    const float f2 = 1.0f / s2;
    const int qrow = q0 + lg * 4 + r;
#pragma unroll
    for (int c = 0; c < 8; ++c) {
      float val = acc1[c][r] * f1 + acc2[c][r] * f2;
      Ob[(size_t)qrow * DMODEL + h * HD + c * 16 + lr] = (__bf16)val;
    }
  }
}

// ---------------- launch ----------------

extern "C" void kernel_launch(void* const* d_in, const int* in_sizes, int n_in,
                              void* d_out, int out_size, void* d_ws, size_t ws_size,
                              hipStream_t stream) {
  const float* x    = (const float*)d_in[0];
  const float* pk   = (const float*)d_in[1];
  const float* pv   = (const float*)d_in[2];
  const float* Wq   = (const float*)d_in[3];
  const float* bq   = (const float*)d_in[4];
  const float* Wk   = (const float*)d_in[5];
  const float* bk   = (const float*)d_in[6];
  const float* Wv   = (const float*)d_in[7];
  const float* bv   = (const float*)d_in[8];
  const float* gate = (const float*)d_in[9];
  const float* Wout = (const float*)d_in[10];
  const float* bout = (const float*)d_in[11];
  float* out = (float*)d_out;

  char* ws = (char*)d_ws;
  size_t off = 0;
  auto alc = [&](size_t bytes) -> char* {
    char* p = ws + off;
    off += bytes;
    off = (off + 255) & ~(size_t)255;
    return p;
  };
  __bf16* xb   = (__bf16*)alc((size_t)DMODEL * DMODEL * 2);
  __bf16* WqT  = (__bf16*)alc((size_t)DMODEL * DMODEL * 2);
  __bf16* WkT  = (__bf16*)alc((size_t)DMODEL * DMODEL * 2);
  __bf16* WvT  = (__bf16*)alc((size_t)DMODEL * DMODEL * 2);
  __bf16* WoT  = (__bf16*)alc((size_t)DMODEL * DMODEL * 2);
  __bf16* Qs   = (__bf16*)alc((size_t)NH * QLEN * HD * 2);
  __bf16* Kall = (__bf16*)alc((size_t)NH * KVLEN * HD * 2);
  __bf16* VTa  = (__bf16*)alc((size_t)NH * HD * KVLEN * 2);
  __bf16* Ob   = (__bf16*)alc((size_t)QLEN * DMODEL * 2);

  dim3 tgrid(32, 32);
  k_transpose_bf16<<<tgrid, 256, 0, stream>>>(Wq, WqT);
  k_transpose_bf16<<<tgrid, 256, 0, stream>>>(Wk, WkT);
  k_transpose_bf16<<<tgrid, 256, 0, stream>>>(Wv, WvT);
  k_transpose_bf16<<<tgrid, 256, 0, stream>>>(Wout, WoT);
  k_f32_to_bf16<<<1024, 256, 0, stream>>>(x, xb, (DMODEL * DMODEL) / 4);
  k_prefix<<<4096, 256, 0, stream>>>(pk, pv, Kall, VTa);

  gemm_qkv<<<768, 256, 0, stream>>>(xb, WqT, WkT, WvT, bq, bk, bv, Qs, Kall, VTa);
  k_attn<<<512, 256, 0, stream>>>(Qs, Kall, VTa, gate, Ob);
  gemm_out<<<512, 256, 0, stream>>>(Ob, WoT, bout, out);
}

// Round 6
// 223.163 us; speedup vs baseline: 1.0918x; 1.0918x over previous
//
#include <hip/hip_runtime.h>
#include <hip/hip_bf16.h>

typedef __bf16 bf16x8 __attribute__((ext_vector_type(8)));
typedef __bf16 bf16x4v __attribute__((ext_vector_type(4)));
typedef float f32x4 __attribute__((ext_vector_type(4)));

#define DMODEL 2048
#define NH 16
#define HD 128
#define PLEN 512
#define QLEN 2048
#define KVLEN 2560

#define FENCE() asm volatile("" ::: "memory")
#define LGKM0() asm volatile("s_waitcnt lgkmcnt(0)" ::: "memory")

__device__ __forceinline__ void gload_lds16(const void* g, void* l) {
  __builtin_amdgcn_global_load_lds((const __attribute__((address_space(1))) void*)g,
                                   (__attribute__((address_space(3))) void*)l, 16, 0, 0);
}

// ---------------- conversion kernels ----------------

// 4 weight matrices f32 [2048][2048] row-major -> bf16 transposed, z-indexed
__global__ __launch_bounds__(256) void k_transpose4(const float* __restrict__ s0,
                                                    const float* __restrict__ s1,
                                                    const float* __restrict__ s2,
                                                    const float* __restrict__ s3,
                                                    __bf16* __restrict__ d0,
                                                    __bf16* __restrict__ d1,
                                                    __bf16* __restrict__ d2,
                                                    __bf16* __restrict__ d3) {
  __shared__ float tile[64][65];
  const int z = blockIdx.z;
  const float* in = (z == 0) ? s0 : (z == 1) ? s1 : (z == 2) ? s2 : s3;
  __bf16* out = (z == 0) ? d0 : (z == 1) ? d1 : (z == 2) ? d2 : d3;
  const int t = threadIdx.x;
  const int tx = t & 63, ty = t >> 6;
  const int r0 = blockIdx.y * 64, c0 = blockIdx.x * 64;
#pragma unroll
  for (int i = 0; i < 16; ++i) {
    int r = ty + i * 4;
    tile[r][tx] = in[(size_t)(r0 + r) * DMODEL + c0 + tx];
  }
  __syncthreads();
#pragma unroll
  for (int i = 0; i < 16; ++i) {
    int r = ty + i * 4;
    out[(size_t)(c0 + r) * DMODEL + r0 + tx] = (__bf16)tile[tx][r];
  }
}

__global__ __launch_bounds__(256) void k_f32_to_bf16(const float* __restrict__ in,
                                                     __bf16* __restrict__ out, int n4) {
  int i = blockIdx.x * blockDim.x + threadIdx.x;
  int stride = gridDim.x * blockDim.x;
  for (; i < n4; i += stride) {
    float4 v = ((const float4*)in)[i];
    bf16x4v o;
    o[0] = (__bf16)v.x; o[1] = (__bf16)v.y; o[2] = (__bf16)v.z; o[3] = (__bf16)v.w;
    ((bf16x4v*)out)[i] = o;
  }
}

// prefix_key/value f32 [512][16][128] -> K[h][p][hd], VT[h][hd][p]  (bf16)
__global__ __launch_bounds__(256) void k_prefix(const float* __restrict__ pk,
                                                const float* __restrict__ pv,
                                                __bf16* __restrict__ Kall,
                                                __bf16* __restrict__ VT) {
  int idx = blockIdx.x * 256 + threadIdx.x;  // 512*16*128 = 1048576 exact
  int hd = idx & 127;
  int h = (idx >> 7) & 15;
  int p = idx >> 11;
  Kall[(size_t)h * KVLEN * HD + (size_t)p * HD + hd] = (__bf16)pk[idx];
  VT[(size_t)h * HD * KVLEN + (size_t)hd * KVLEN + p] = (__bf16)pv[idx];
}

// ---------------- GEMM: C[128 x BN] = A[M,K] * BT[N,K]^T, double-buffered ----------------
// (round-4 proven structure: 2-buf, __syncthreads, setprio on MFMA cluster)

template <int BN>
__device__ __forceinline__ void stage_tile(const __bf16* __restrict__ A,
                                           const __bf16* __restrict__ BT,
                                           char* AsmB, char* BsmB,
                                           int m0, int n0, int k0, int w, int l) {
#pragma unroll
  for (int i = 0; i < 2; ++i) {  // A: 128x32 bf16 = 8KB
    int base = i * 4096 + w * 1024;
    int o = base + l * 16;
    int row = o >> 6, col = (o & 63) >> 1;
    gload_lds16(A + (size_t)(m0 + row) * DMODEL + k0 + col, AsmB + base);
  }
  if constexpr (BN == 128) {
#pragma unroll
    for (int i = 0; i < 2; ++i) {
      int base = i * 4096 + w * 1024;
      int o = base + l * 16;
      int row = o >> 6, col = (o & 63) >> 1;
      gload_lds16(BT + (size_t)(n0 + row) * DMODEL + k0 + col, BsmB + base);
    }
  } else {  // BN==64: 4KB
    int base = w * 1024;
    int o = base + l * 16;
    int row = o >> 6, col = (o & 63) >> 1;
    gload_lds16(BT + (size_t)(n0 + row) * DMODEL + k0 + col, BsmB + base);
  }
}

template <int BN>
__device__ __forceinline__ void gemm_mainloop_db(const __bf16* __restrict__ A,
                                                 const __bf16* __restrict__ BT,
                                                 __bf16* Asm, __bf16* Bsm,  // [2][...]
                                                 int m0, int n0, int w, int l,
                                                 f32x4 (&acc)[4][BN / 32]) {
  constexpr int NI = BN / 32;
  constexpr int ABUF = 4096;
  constexpr int BBUF = BN * 32;
  const int lr = l & 15, lg = l >> 4;
  int cur = 0;
  stage_tile<BN>(A, BT, (char*)Asm, (char*)Bsm, m0, n0, 0, w, l);
  __syncthreads();
  for (int k0 = 0; k0 < DMODEL; k0 += 32) {
    if (k0 + 32 < DMODEL)
      stage_tile<BN>(A, BT, (char*)(Asm + (cur ^ 1) * ABUF), (char*)(Bsm + (cur ^ 1) * BBUF),
                     m0, n0, k0 + 32, w, l);
    const __bf16* Ab = Asm + cur * ABUF;
    const __bf16* Bb = Bsm + cur * BBUF;
    bf16x8 af[4], bfv[NI];
#pragma unroll
    for (int mi = 0; mi < 4; ++mi)
      af[mi] = *(const bf16x8*)(Ab + ((w >> 1) * 64 + mi * 16 + lr) * 32 + lg * 8);
#pragma unroll
    for (int ni = 0; ni < NI; ++ni)
      bfv[ni] = *(const bf16x8*)(Bb + ((w & 1) * (BN / 2) + ni * 16 + lr) * 32 + lg * 8);
    __builtin_amdgcn_s_setprio(1);
#pragma unroll
    for (int mi = 0; mi < 4; ++mi)
#pragma unroll
      for (int ni = 0; ni < NI; ++ni)
        acc[mi][ni] = __builtin_amdgcn_mfma_f32_16x16x32_bf16(af[mi], bfv[ni], acc[mi][ni], 0, 0, 0);
    __builtin_amdgcn_s_setprio(0);
    __syncthreads();
    cur ^= 1;
  }
}

// z=0: Q (scaled 1/sqrt(128)) -> Qs[h][q][hd]; z=1: K -> Kall[h][512+q][hd]; z=2: V -> VT[h][hd][512+q]
__global__ __launch_bounds__(256) void gemm_qkv(const __bf16* __restrict__ xb,
                                                const __bf16* __restrict__ WqT,
                                                const __bf16* __restrict__ WkT,
                                                const __bf16* __restrict__ WvT,
                                                const float* __restrict__ bq,
                                                const float* __restrict__ bk,
                                                const float* __restrict__ bv,
                                                __bf16* __restrict__ Qs,
                                                __bf16* __restrict__ Kall,
                                                __bf16* __restrict__ VT) {
  __shared__ __bf16 Asm[2][4096];
  __shared__ __bf16 Bsm[2][4096];
  const int t = threadIdx.x, w = t >> 6, l = t & 63;
  const int m0 = blockIdx.x * 128, n0 = blockIdx.y * 128;
  const int z = blockIdx.z;
  const __bf16* BT = (z == 0) ? WqT : ((z == 1) ? WkT : WvT);
  const float* bias = (z == 0) ? bq : ((z == 1) ? bk : bv);
  f32x4 acc[4][4];
#pragma unroll
  for (int mi = 0; mi < 4; ++mi)
#pragma unroll
    for (int ni = 0; ni < 4; ++ni) acc[mi][ni] = (f32x4){0.f, 0.f, 0.f, 0.f};
  gemm_mainloop_db<128>(xb, BT, &Asm[0][0], &Bsm[0][0], m0, n0, w, l, acc);
  const int lr = l & 15, lg = l >> 4;
#pragma unroll
  for (int mi = 0; mi < 4; ++mi)
#pragma unroll
    for (int ni = 0; ni < 4; ++ni)
#pragma unroll
      for (int r = 0; r < 4; ++r) {
        int row = m0 + (w >> 1) * 64 + mi * 16 + lg * 4 + r;
        int col = n0 + (w & 1) * 64 + ni * 16 + lr;
        float v = acc[mi][ni][r] + bias[col];
        int hh = col >> 7, hd = col & 127;
        if (z == 0) {
          Qs[(size_t)hh * QLEN * HD + (size_t)row * HD + hd] = (__bf16)(v * 0.08838834764831845f);
        } else if (z == 1) {
          Kall[(size_t)hh * KVLEN * HD + (size_t)(PLEN + row) * HD + hd] = (__bf16)v;
        } else {
          VT[(size_t)hh * HD * KVLEN + (size_t)hd * KVLEN + (PLEN + row)] = (__bf16)v;
        }
      }
}

// final: out[q][d] = O[q][:] . WoT[d][:] + bout[d]  (f32 out).  128x64 tiles, 512 blocks.
__global__ __launch_bounds__(256) void gemm_out(const __bf16* __restrict__ Ob,
                                                const __bf16* __restrict__ WoT,
                                                const float* __restrict__ bout,
                                                float* __restrict__ out) {
  __shared__ __bf16 Asm[2][4096];
  __shared__ __bf16 Bsm[2][2048];
  const int t = threadIdx.x, w = t >> 6, l = t & 63;
  const int m0 = blockIdx.x * 128, n0 = blockIdx.y * 64;
  f32x4 acc[4][2];
#pragma unroll
  for (int mi = 0; mi < 4; ++mi)
#pragma unroll
    for (int ni = 0; ni < 2; ++ni) acc[mi][ni] = (f32x4){0.f, 0.f, 0.f, 0.f};
  gemm_mainloop_db<64>(Ob, WoT, &Asm[0][0], &Bsm[0][0], m0, n0, w, l, acc);
  const int lr = l & 15, lg = l >> 4;
#pragma unroll
  for (int mi = 0; mi < 4; ++mi)
#pragma unroll
    for (int ni = 0; ni < 2; ++ni)
#pragma unroll
      for (int r = 0; r < 4; ++r) {
        int row = m0 + (w >> 1) * 64 + mi * 16 + lg * 4 + r;
        int col = n0 + (w & 1) * 32 + ni * 16 + lr;
        out[(size_t)row * DMODEL + col] = acc[mi][ni][r] + bout[col];
      }
}

// ---------------- attention (software-pipelined: QK one tile ahead) ----------------
// grid (32,16): bx, head; qt=(h<8)?bx:31-bx pairs long+short blocks per CU.
// 4 waves, wave w owns q rows [qt*64+w*16, +16). Unified tile stream (prefix keys
// 0..511 contiguous with suffix in Kall/VT): tile i = keys [32i, 32i+32).
// 3 single-tile buffers, counted vmcnt(4) (4 stage-loads/wave/tile): at iter i,
// tiles i AND i+1 are resident -> issue QK(i+1) MFMAs BEFORE softmax(i)+PV(i) so
// the independent MFMA work overlaps the exp/cvt VALU chain (T15-style dep-break).
// Fixed-max softmax exp(S-16): |logit| <= ~12 by Cauchy-Schwarz (q pre-scaled).
__global__ __launch_bounds__(256, 2) void k_attn(const __bf16* __restrict__ Qs,
                                                 const __bf16* __restrict__ Kall,
                                                 const __bf16* __restrict__ VT,
                                                 const float* __restrict__ gate,
                                                 __bf16* __restrict__ Ob) {
  __shared__ __bf16 Ksm[3][4096];   // [buf][32 kv][128 hd] (xor-swizzled)
  __shared__ __bf16 Vsm[3][4096];   // [buf][128 hd][32 kv] (xor-swizzled)
  __shared__ __bf16 Pl[4][16 * 40]; // per-wave P tile, stride 40
  const int h = blockIdx.y;
  const int qt = (h < 8) ? blockIdx.x : (31 - blockIdx.x);
  const int t = threadIdx.x, w = t >> 6, l = t & 63;
  const int lr = l & 15, lg = l >> 4;
  const int q0 = qt * 64 + w * 16;
  const __bf16* Qh = Qs + (size_t)h * QLEN * HD;
  const char* Khb = (const char*)(Kall + (size_t)h * KVLEN * HD);
  const char* Vhb = (const char*)(VT + (size_t)h * HD * KVLEN);
  __bf16* Pw = &Pl[w][0];

  bf16x8 qf[4];
#pragma unroll
  for (int c = 0; c < 4; ++c)
    qf[c] = *(const bf16x8*)(Qh + (size_t)(q0 + lr) * HD + c * 32 + lg * 8);

  f32x4 acc1[8], acc2[8];
  float ss1[4], ss2[4];
#pragma unroll
  for (int c = 0; c < 8; ++c) {
    acc1[c] = (f32x4){0.f, 0.f, 0.f, 0.f};
    acc2[c] = (f32x4){0.f, 0.f, 0.f, 0.f};
  }
#pragma unroll
  for (int r = 0; r < 4; ++r) { ss1[r] = 0.f; ss2[r] = 0.f; }

  // stage 32-key tile (keys kb..kb+31) into buffer `buf`; 4 vmem instr per wave
  auto STAGE = [&](int buf, int kb) {
#pragma unroll
    for (int i = 0; i < 2; ++i) {  // K: 8KB, rows contiguous in global
      int o = (i * 256 + w * 64 + l) * 16;
      int po = o ^ (((o >> 8) & 7) << 4);
      gload_lds16(Khb + (size_t)kb * 256 + po, (char*)&Ksm[buf][0] + i * 4096 + w * 1024);
    }
#pragma unroll
    for (int i = 0; i < 2; ++i) {  // V: 8KB, rows strided KVLEN*2 in global VT
      int o = (i * 256 + w * 64 + l) * 16;
      int po = o ^ (((o >> 7) & 7) << 4);
      int row = po >> 6, colb = po & 63;
      gload_lds16(Vhb + (size_t)row * (KVLEN * 2) + (size_t)kb * 2 + colb,
                  (char*)&Vsm[buf][0] + i * 4096 + w * 1024);
    }
  };

  // QK^T for one staged tile -> s0 (keys 0-15), s1 (keys 16-31)
  auto QK = [&](int buf, f32x4& s0, f32x4& s1) {
    const char* Kb = (const char*)&Ksm[buf][0];
    s0 = (f32x4){0.f, 0.f, 0.f, 0.f};
    s1 = (f32x4){0.f, 0.f, 0.f, 0.f};
    __builtin_amdgcn_s_setprio(1);
#pragma unroll
    for (int c = 0; c < 4; ++c) {
      int o0 = lr * 256 + c * 64 + lg * 16;        o0 ^= ((o0 >> 8) & 7) << 4;
      int o1 = (16 + lr) * 256 + c * 64 + lg * 16; o1 ^= ((o1 >> 8) & 7) << 4;
      bf16x8 kf0 = *(const bf16x8*)(Kb + o0);
      bf16x8 kf1 = *(const bf16x8*)(Kb + o1);
      s0 = __builtin_amdgcn_mfma_f32_16x16x32_bf16(qf[c], kf0, s0, 0, 0, 0);
      s1 = __builtin_amdgcn_mfma_f32_16x16x32_bf16(qf[c], kf1, s1, 0, 0, 0);
    }
    __builtin_amdgcn_s_setprio(0);
  };

  // softmax + PV for tile whose scores are (s0,s1); V from buffer `buf`
  auto SMPV = [&](int buf, f32x4 s0, f32x4 s1, int mrel, bool domask,
                  f32x4 (&ACC)[8], float (&SS)[4]) {
    const char* Vb = (const char*)&Vsm[buf][0];
#pragma unroll
    for (int r = 0; r < 4; ++r) {
      if (domask) {
        int qq = q0 + lg * 4 + r;
        if (mrel + lr > qq) s0[r] = -1e30f;
        if (mrel + 16 + lr > qq) s1[r] = -1e30f;
      }
      float p0 = __expf(s0[r] - 16.0f);
      float p1 = __expf(s1[r] - 16.0f);
      SS[r] += p0 + p1;
      Pw[(lg * 4 + r) * 40 + lr] = (__bf16)p0;
      Pw[(lg * 4 + r) * 40 + 16 + lr] = (__bf16)p1;
    }
    bf16x8 pf = *(const bf16x8*)(Pw + lr * 40 + lg * 8);
    __builtin_amdgcn_s_setprio(1);
#pragma unroll
    for (int c = 0; c < 8; ++c) {
      int o = (c * 16 + lr) * 64 + lg * 16; o ^= ((o >> 7) & 7) << 4;
      bf16x8 vf = *(const bf16x8*)(Vb + o);
      ACC[c] = __builtin_amdgcn_mfma_f32_16x16x32_bf16(pf, vf, ACC[c], 0, 0, 0);
    }
    __builtin_amdgcn_s_setprio(0);
  };

  // ---- pipelined loop: tile i = keys [32i, 32i+32); i<16 prefix, else causal suffix ----
  const int NT = 16 + 2 * qt + 2;
  STAGE(0, 0);
  STAGE(1, 32);
  asm volatile("s_waitcnt vmcnt(4)" ::: "memory");   // tile 0 resident
  FENCE(); __builtin_amdgcn_s_barrier(); FENCE();
  f32x4 stA, stB;
  QK(0, stA, stB);
#pragma unroll 1
  for (int i = 0; i < NT; ++i) {
    int it = i + 2; if (it > NT - 1) it = NT - 1;    // dummy re-stage at tail
    int b2 = i + 2; while (b2 >= 3) b2 -= 3;
    STAGE(b2, it * 32);
    asm volatile("s_waitcnt vmcnt(4)" ::: "memory"); // tiles i, i+1 resident
    FENCE(); __builtin_amdgcn_s_barrier(); FENCE();
    f32x4 c0 = stA, c1 = stB;                        // tile i's scores
    if (i + 1 < NT) {
      int b1 = i + 1; while (b1 >= 3) b1 -= 3;
      QK(b1, stA, stB);                              // independent MFMA work ahead
    }
    int b0 = i; while (b0 >= 3) b0 -= 3;
    if (i < 16) {
      SMPV(b0, c0, c1, 0, false, acc1, ss1);
    } else {
      const int mrel = (i - 16) * 32;
      SMPV(b0, c0, c1, mrel, mrel + 31 > q0, acc2, ss2);
    }
    LGKM0();
    FENCE(); __builtin_amdgcn_s_barrier(); FENCE();
  }

  // ---- epilogue: Ob = gate*acc1/s1 + acc2/s2 ----
  const float g = gate[h];
#pragma unroll
  for (int r = 0; r < 4; ++r) {
    float s1 = ss1[r];
    s1 += __shfl_xor(s1, 1); s1 += __shfl_xor(s1, 2);
    s1 += __shfl_xor(s1, 4); s1 += __shfl_xor(s1, 8);
    float s2 = ss2[r];
    s2 += __shfl_xor(s2, 1); s2 += __shfl_xor(s2, 2);
    s2 += __shfl_xor(s2, 4); s2 += __shfl_xor(s2, 8);
    const float f1 = g / s1;
    const float f2 = 1.0f / s2;
    const int qrow = q0 + lg * 4 + r;
#pragma unroll
    for (int c = 0; c < 8; ++c) {
      float val = acc1[c][r] * f1 + acc2[c][r] * f2;
      Ob[(size_t)qrow * DMODEL + h * HD + c * 16 + lr] = (__bf16)val;
    }
  }
}

// ---------------- launch ----------------

extern "C" void kernel_launch(void* const* d_in, const int* in_sizes, int n_in,
                              void* d_out, int out_size, void* d_ws, size_t ws_size,
                              hipStream_t stream) {
  const float* x    = (const float*)d_in[0];
  const float* pk   = (const float*)d_in[1];
  const float* pv   = (const float*)d_in[2];
  const float* Wq   = (const float*)d_in[3];
  const float* bq   = (const float*)d_in[4];
  const float* Wk   = (const float*)d_in[5];
  const float* bk   = (const float*)d_in[6];
  const float* Wv   = (const float*)d_in[7];
  const float* bv   = (const float*)d_in[8];
  const float* gate = (const float*)d_in[9];
  const float* Wout = (const float*)d_in[10];
  const float* bout = (const float*)d_in[11];
  float* out = (float*)d_out;

  char* ws = (char*)d_ws;
  size_t off = 0;
  auto alc = [&](size_t bytes) -> char* {
    char* p = ws + off;
    off += bytes;
    off = (off + 255) & ~(size_t)255;
    return p;
  };
  __bf16* xb   = (__bf16*)alc((size_t)DMODEL * DMODEL * 2);
  __bf16* WqT  = (__bf16*)alc((size_t)DMODEL * DMODEL * 2);
  __bf16* WkT  = (__bf16*)alc((size_t)DMODEL * DMODEL * 2);
  __bf16* WvT  = (__bf16*)alc((size_t)DMODEL * DMODEL * 2);
  __bf16* WoT  = (__bf16*)alc((size_t)DMODEL * DMODEL * 2);
  __bf16* Qs   = (__bf16*)alc((size_t)NH * QLEN * HD * 2);
  __bf16* Kall = (__bf16*)alc((size_t)NH * KVLEN * HD * 2);
  __bf16* VTa  = (__bf16*)alc((size_t)NH * HD * KVLEN * 2);
  __bf16* Ob   = (__bf16*)alc((size_t)QLEN * DMODEL * 2);

  k_transpose4<<<dim3(32, 32, 4), 256, 0, stream>>>(Wq, Wk, Wv, Wout, WqT, WkT, WvT, WoT);
  k_f32_to_bf16<<<1024, 256, 0, stream>>>(x, xb, (DMODEL * DMODEL) / 4);
  k_prefix<<<4096, 256, 0, stream>>>(pk, pv, Kall, VTa);

  gemm_qkv<<<dim3(16, 16, 3), 256, 0, stream>>>(xb, WqT, WkT, WvT, bq, bk, bv, Qs, Kall, VTa);
  k_attn<<<dim3(32, 16), 256, 0, stream>>>(Qs, Kall, VTa, gate, Ob);
  gemm_out<<<dim3(16, 32), 256, 0, stream>>>(Ob, WoT, bout, out);
}

// Round 7
// 194.992 us; speedup vs baseline: 1.2496x; 1.1445x over previous
//
#include <hip/hip_runtime.h>
#include <hip/hip_bf16.h>

typedef __bf16 bf16x8 __attribute__((ext_vector_type(8)));
typedef __bf16 bf16x4v __attribute__((ext_vector_type(4)));
typedef float f32x4 __attribute__((ext_vector_type(4)));

#define DMODEL 2048
#define NH 16
#define HD 128
#define PLEN 512
#define QLEN 2048
#define KVLEN 2560

__device__ __forceinline__ void gload_lds16(const void* g, void* l) {
  __builtin_amdgcn_global_load_lds((const __attribute__((address_space(1))) void*)g,
                                   (__attribute__((address_space(3))) void*)l, 16, 0, 0);
}

// ---------------- conversion kernels ----------------

// 4 weight matrices f32 [2048][2048] row-major -> bf16 transposed, z-indexed
__global__ __launch_bounds__(256) void k_transpose4(const float* __restrict__ s0,
                                                    const float* __restrict__ s1,
                                                    const float* __restrict__ s2,
                                                    const float* __restrict__ s3,
                                                    __bf16* __restrict__ d0,
                                                    __bf16* __restrict__ d1,
                                                    __bf16* __restrict__ d2,
                                                    __bf16* __restrict__ d3) {
  __shared__ float tile[64][65];
  const int z = blockIdx.z;
  const float* in = (z == 0) ? s0 : (z == 1) ? s1 : (z == 2) ? s2 : s3;
  __bf16* out = (z == 0) ? d0 : (z == 1) ? d1 : (z == 2) ? d2 : d3;
  const int t = threadIdx.x;
  const int tx = t & 63, ty = t >> 6;
  const int r0 = blockIdx.y * 64, c0 = blockIdx.x * 64;
#pragma unroll
  for (int i = 0; i < 16; ++i) {
    int r = ty + i * 4;
    tile[r][tx] = in[(size_t)(r0 + r) * DMODEL + c0 + tx];
  }
  __syncthreads();
#pragma unroll
  for (int i = 0; i < 16; ++i) {
    int r = ty + i * 4;
    out[(size_t)(c0 + r) * DMODEL + r0 + tx] = (__bf16)tile[tx][r];
  }
}

__global__ __launch_bounds__(256) void k_f32_to_bf16(const float* __restrict__ in,
                                                     __bf16* __restrict__ out, int n4) {
  int i = blockIdx.x * blockDim.x + threadIdx.x;
  int stride = gridDim.x * blockDim.x;
  for (; i < n4; i += stride) {
    float4 v = ((const float4*)in)[i];
    bf16x4v o;
    o[0] = (__bf16)v.x; o[1] = (__bf16)v.y; o[2] = (__bf16)v.z; o[3] = (__bf16)v.w;
    ((bf16x4v*)out)[i] = o;
  }
}

// prefix_key/value f32 [512][16][128] -> K[h][p][hd], VT[h][hd][p]  (bf16)
__global__ __launch_bounds__(256) void k_prefix(const float* __restrict__ pk,
                                                const float* __restrict__ pv,
                                                __bf16* __restrict__ Kall,
                                                __bf16* __restrict__ VT) {
  int idx = blockIdx.x * 256 + threadIdx.x;  // 512*16*128 = 1048576 exact
  int hd = idx & 127;
  int h = (idx >> 7) & 15;
  int p = idx >> 11;
  Kall[(size_t)h * KVLEN * HD + (size_t)p * HD + hd] = (__bf16)pk[idx];
  VT[(size_t)h * HD * KVLEN + (size_t)hd * KVLEN + p] = (__bf16)pv[idx];
}

// ---------------- GEMM: C[128 x BN] = A[M,K] * BT[N,K]^T, double-buffered ----------------
// (round-4 proven structure: 2-buf, __syncthreads, setprio on MFMA cluster)

template <int BN>
__device__ __forceinline__ void stage_tile(const __bf16* __restrict__ A,
                                           const __bf16* __restrict__ BT,
                                           char* AsmB, char* BsmB,
                                           int m0, int n0, int k0, int w, int l) {
#pragma unroll
  for (int i = 0; i < 2; ++i) {  // A: 128x32 bf16 = 8KB
    int base = i * 4096 + w * 1024;
    int o = base + l * 16;
    int row = o >> 6, col = (o & 63) >> 1;
    gload_lds16(A + (size_t)(m0 + row) * DMODEL + k0 + col, AsmB + base);
  }
  if constexpr (BN == 128) {
#pragma unroll
    for (int i = 0; i < 2; ++i) {
      int base = i * 4096 + w * 1024;
      int o = base + l * 16;
      int row = o >> 6, col = (o & 63) >> 1;
      gload_lds16(BT + (size_t)(n0 + row) * DMODEL + k0 + col, BsmB + base);
    }
  } else {  // BN==64: 4KB
    int base = w * 1024;
    int o = base + l * 16;
    int row = o >> 6, col = (o & 63) >> 1;
    gload_lds16(BT + (size_t)(n0 + row) * DMODEL + k0 + col, BsmB + base);
  }
}

template <int BN>
__device__ __forceinline__ void gemm_mainloop_db(const __bf16* __restrict__ A,
                                                 const __bf16* __restrict__ BT,
                                                 __bf16* Asm, __bf16* Bsm,  // [2][...]
                                                 int m0, int n0, int w, int l,
                                                 f32x4 (&acc)[4][BN / 32]) {
  constexpr int NI = BN / 32;
  constexpr int ABUF = 4096;
  constexpr int BBUF = BN * 32;
  const int lr = l & 15, lg = l >> 4;
  int cur = 0;
  stage_tile<BN>(A, BT, (char*)Asm, (char*)Bsm, m0, n0, 0, w, l);
  __syncthreads();
  for (int k0 = 0; k0 < DMODEL; k0 += 32) {
    if (k0 + 32 < DMODEL)
      stage_tile<BN>(A, BT, (char*)(Asm + (cur ^ 1) * ABUF), (char*)(Bsm + (cur ^ 1) * BBUF),
                     m0, n0, k0 + 32, w, l);
    const __bf16* Ab = Asm + cur * ABUF;
    const __bf16* Bb = Bsm + cur * BBUF;
    bf16x8 af[4], bfv[NI];
#pragma unroll
    for (int mi = 0; mi < 4; ++mi)
      af[mi] = *(const bf16x8*)(Ab + ((w >> 1) * 64 + mi * 16 + lr) * 32 + lg * 8);
#pragma unroll
    for (int ni = 0; ni < NI; ++ni)
      bfv[ni] = *(const bf16x8*)(Bb + ((w & 1) * (BN / 2) + ni * 16 + lr) * 32 + lg * 8);
    __builtin_amdgcn_s_setprio(1);
#pragma unroll
    for (int mi = 0; mi < 4; ++mi)
#pragma unroll
      for (int ni = 0; ni < NI; ++ni)
        acc[mi][ni] = __builtin_amdgcn_mfma_f32_16x16x32_bf16(af[mi], bfv[ni], acc[mi][ni], 0, 0, 0);
    __builtin_amdgcn_s_setprio(0);
    __syncthreads();
    cur ^= 1;
  }
}

// z=0: Q (scaled 1/sqrt(128)) -> Qs[h][q][hd]; z=1: K -> Kall[h][512+q][hd]; z=2: V -> VT[h][hd][512+q]
__global__ __launch_bounds__(256) void gemm_qkv(const __bf16* __restrict__ xb,
                                                const __bf16* __restrict__ WqT,
                                                const __bf16* __restrict__ WkT,
                                                const __bf16* __restrict__ WvT,
                                                const float* __restrict__ bq,
                                                const float* __restrict__ bk,
                                                const float* __restrict__ bv,
                                                __bf16* __restrict__ Qs,
                                                __bf16* __restrict__ Kall,
                                                __bf16* __restrict__ VT) {
  __shared__ __bf16 Asm[2][4096];
  __shared__ __bf16 Bsm[2][4096];
  const int t = threadIdx.x, w = t >> 6, l = t & 63;
  const int m0 = blockIdx.x * 128, n0 = blockIdx.y * 128;
  const int z = blockIdx.z;
  const __bf16* BT = (z == 0) ? WqT : ((z == 1) ? WkT : WvT);
  const float* bias = (z == 0) ? bq : ((z == 1) ? bk : bv);
  f32x4 acc[4][4];
#pragma unroll
  for (int mi = 0; mi < 4; ++mi)
#pragma unroll
    for (int ni = 0; ni < 4; ++ni) acc[mi][ni] = (f32x4){0.f, 0.f, 0.f, 0.f};
  gemm_mainloop_db<128>(xb, BT, &Asm[0][0], &Bsm[0][0], m0, n0, w, l, acc);
  const int lr = l & 15, lg = l >> 4;
#pragma unroll
  for (int mi = 0; mi < 4; ++mi)
#pragma unroll
    for (int ni = 0; ni < 4; ++ni)
#pragma unroll
      for (int r = 0; r < 4; ++r) {
        int row = m0 + (w >> 1) * 64 + mi * 16 + lg * 4 + r;
        int col = n0 + (w & 1) * 64 + ni * 16 + lr;
        float v = acc[mi][ni][r] + bias[col];
        int hh = col >> 7, hd = col & 127;
        if (z == 0) {
          Qs[(size_t)hh * QLEN * HD + (size_t)row * HD + hd] = (__bf16)(v * 0.08838834764831845f);
        } else if (z == 1) {
          Kall[(size_t)hh * KVLEN * HD + (size_t)(PLEN + row) * HD + hd] = (__bf16)v;
        } else {
          VT[(size_t)hh * HD * KVLEN + (size_t)hd * KVLEN + (PLEN + row)] = (__bf16)v;
        }
      }
}

// final: out[q][d] = O[q][:] . WoT[d][:] + bout[d]  (f32 out).  128x64 tiles, 512 blocks.
__global__ __launch_bounds__(256) void gemm_out(const __bf16* __restrict__ Ob,
                                                const __bf16* __restrict__ WoT,
                                                const float* __restrict__ bout,
                                                float* __restrict__ out) {
  __shared__ __bf16 Asm[2][4096];
  __shared__ __bf16 Bsm[2][2048];
  const int t = threadIdx.x, w = t >> 6, l = t & 63;
  const int m0 = blockIdx.x * 128, n0 = blockIdx.y * 64;
  f32x4 acc[4][2];
#pragma unroll
  for (int mi = 0; mi < 4; ++mi)
#pragma unroll
    for (int ni = 0; ni < 2; ++ni) acc[mi][ni] = (f32x4){0.f, 0.f, 0.f, 0.f};
  gemm_mainloop_db<64>(Ob, WoT, &Asm[0][0], &Bsm[0][0], m0, n0, w, l, acc);
  const int lr = l & 15, lg = l >> 4;
#pragma unroll
  for (int mi = 0; mi < 4; ++mi)
#pragma unroll
    for (int ni = 0; ni < 2; ++ni)
#pragma unroll
      for (int r = 0; r < 4; ++r) {
        int row = m0 + (w >> 1) * 64 + mi * 16 + lg * 4 + r;
        int col = n0 + (w & 1) * 32 + ni * 16 + lr;
        out[(size_t)row * DMODEL + col] = acc[mi][ni][r] + bout[col];
      }
}

// ---------------- attention (r3-proven machinery + CU-balanced work mapping) ----------------
// Flat grid 512*KS. Decode (KS=2): b=id&255, k=id>>8, h=b>>4, m=b&15;
//   k=0:(z0,qt=2m) k=1:(z0,31-2m) k=2:(z1,2m+1) k=3:(z1,30-2m)  — bijective, and the
// 4 blocks a CU receives under round-robin dispatch {c,c+256,c+512,c+768} share (h,m)
// => their suffix tile counts sum to a CONSTANT (132) regardless of m -> no CU imbalance.
// 4 waves/block, wave w owns q rows [qt*64+w*16, +16). K/V staged via global_load_lds
// (linear LDS dest, pre-swizzled global source, XOR involutions). 2-buf, one
// __syncthreads per tile (proven r3 pipeline). Split z handles tiles tt ≡ z (mod KS);
// fixed-max softmax exp(S-16) => partials combine by pure addition in k_combine.
template <int KS>
__global__ __launch_bounds__(256, 4) void k_attn(const __bf16* __restrict__ Qs,
                                                 const __bf16* __restrict__ Kall,
                                                 const __bf16* __restrict__ VT,
                                                 __bf16* __restrict__ P1buf,
                                                 float* __restrict__ S1buf,
                                                 __bf16* __restrict__ P2buf,
                                                 float* __restrict__ S2buf) {
  __shared__ __bf16 Ksm[2][4096];   // [buf][32 kv][128 hd] (xor-swizzled)
  __shared__ __bf16 Vsm[2][4096];   // [buf][128 hd][32 kv] (xor-swizzled)
  __shared__ __bf16 Pl[4][16 * 40]; // per-wave P tile, stride 40
  const int id = blockIdx.x;
  const int b = id & 255, k = id >> 8;
  const int h = b >> 4, m = b & 15;
  int qt, z;
  if constexpr (KS == 2) {
    z = k >> 1;
    const int j = 2 * m + (k >> 1);
    qt = (k & 1) ? (31 - j) : j;
  } else {
    z = 0;
    qt = (k & 1) ? (31 - 2 * m) : (2 * m);
  }
  const int t = threadIdx.x, w = t >> 6, l = t & 63;
  const int lr = l & 15, lg = l >> 4;
  const int q0 = qt * 64 + w * 16;
  const __bf16* Qh = Qs + (size_t)h * QLEN * HD;
  const char* Khb = (const char*)(Kall + (size_t)h * KVLEN * HD);
  const char* Vhb = (const char*)(VT + (size_t)h * HD * KVLEN);
  __bf16* Pw = &Pl[w][0];

  bf16x8 qf[4];
#pragma unroll
  for (int c = 0; c < 4; ++c)
    qf[c] = *(const bf16x8*)(Qh + (size_t)(q0 + lr) * HD + c * 32 + lg * 8);

  f32x4 acc[8];
  float ss[4];

  // stage 32-key tile (keys kb..kb+31) into buffer `buf`
  auto STAGE = [&](int buf, int kb) {
#pragma unroll
    for (int i = 0; i < 2; ++i) {  // K: 8KB, rows contiguous in global
      int o = (i * 256 + w * 64 + l) * 16;
      int po = o ^ (((o >> 8) & 7) << 4);
      gload_lds16(Khb + (size_t)kb * 256 + po, (char*)&Ksm[buf][0] + i * 4096 + w * 1024);
    }
#pragma unroll
    for (int i = 0; i < 2; ++i) {  // V: 8KB, rows strided KVLEN*2 in global VT
      int o = (i * 256 + w * 64 + l) * 16;
      int po = o ^ (((o >> 7) & 7) << 4);
      int row = po >> 6, colb = po & 63;
      gload_lds16(Vhb + (size_t)row * (KVLEN * 2) + (size_t)kb * 2 + colb,
                  (char*)&Vsm[buf][0] + i * 4096 + w * 1024);
    }
  };

  // compute one staged tile; mrel = suffix-relative key base (only used if domask)
  auto COMPUTE = [&](int buf, int mrel, bool domask) {
    const char* Kb = (const char*)&Ksm[buf][0];
    const char* Vb = (const char*)&Vsm[buf][0];
    f32x4 st0 = {0.f, 0.f, 0.f, 0.f}, st1 = {0.f, 0.f, 0.f, 0.f};
    __builtin_amdgcn_s_setprio(1);
#pragma unroll
    for (int c = 0; c < 4; ++c) {
      int o0 = lr * 256 + c * 64 + lg * 16;        o0 ^= ((o0 >> 8) & 7) << 4;
      int o1 = (16 + lr) * 256 + c * 64 + lg * 16; o1 ^= ((o1 >> 8) & 7) << 4;
      bf16x8 kf0 = *(const bf16x8*)(Kb + o0);
      bf16x8 kf1 = *(const bf16x8*)(Kb + o1);
      st0 = __builtin_amdgcn_mfma_f32_16x16x32_bf16(qf[c], kf0, st0, 0, 0, 0);
      st1 = __builtin_amdgcn_mfma_f32_16x16x32_bf16(qf[c], kf1, st1, 0, 0, 0);
    }
    __builtin_amdgcn_s_setprio(0);
#pragma unroll
    for (int r = 0; r < 4; ++r) {
      if (domask) {
        int qq = q0 + lg * 4 + r;
        if (mrel + lr > qq) st0[r] = -1e30f;
        if (mrel + 16 + lr > qq) st1[r] = -1e30f;
      }
      float p0 = __expf(st0[r] - 16.0f);
      float p1 = __expf(st1[r] - 16.0f);
      ss[r] += p0 + p1;
      Pw[(lg * 4 + r) * 40 + lr] = (__bf16)p0;
      Pw[(lg * 4 + r) * 40 + 16 + lr] = (__bf16)p1;
    }
    bf16x8 pf = *(const bf16x8*)(Pw + lr * 40 + lg * 8);
    __builtin_amdgcn_s_setprio(1);
#pragma unroll
    for (int c = 0; c < 8; ++c) {
      int o = (c * 16 + lr) * 64 + lg * 16; o ^= ((o >> 7) & 7) << 4;
      bf16x8 vf = *(const bf16x8*)(Vb + o);
      acc[c] = __builtin_amdgcn_mfma_f32_16x16x32_bf16(pf, vf, acc[c], 0, 0, 0);
    }
    __builtin_amdgcn_s_setprio(0);
  };

  auto STORE_PHASE = [&](__bf16* PBUF, float* SBUF) {
    const size_t rb = (size_t)(z * NH + h) * QLEN;
#pragma unroll
    for (int r = 0; r < 4; ++r) {
      float s = ss[r];
      s += __shfl_xor(s, 1); s += __shfl_xor(s, 2);
      s += __shfl_xor(s, 4); s += __shfl_xor(s, 8);
      const int row = q0 + lg * 4 + r;
      if (lr == 0) SBUF[rb + row] = s;
#pragma unroll
      for (int c = 0; c < 8; ++c)
        PBUF[(rb + row) * HD + c * 16 + lr] = (__bf16)acc[c][r];
    }
  };

  // ---- phase 1: prefix, tiles tt ≡ z (mod KS), tt < 16, unmasked ----
#pragma unroll
  for (int c = 0; c < 8; ++c) acc[c] = (f32x4){0.f, 0.f, 0.f, 0.f};
#pragma unroll
  for (int r = 0; r < 4; ++r) ss[r] = 0.f;
  int cur = 0;
  STAGE(0, z * 32);
  __syncthreads();
#pragma unroll 1
  for (int tt = z; tt < 16; tt += KS) {
    if (tt + KS < 16) STAGE(cur ^ 1, (tt + KS) * 32);
    else STAGE(cur ^ 1, PLEN + z * 32);          // phase-2 prologue
    COMPUTE(cur, 0, false);
    __syncthreads();
    cur ^= 1;
  }
  STORE_PHASE(P1buf, S1buf);

  // ---- phase 2: causal suffix (buffer `cur` already staged) ----
#pragma unroll
  for (int c = 0; c < 8; ++c) acc[c] = (f32x4){0.f, 0.f, 0.f, 0.f};
#pragma unroll
  for (int r = 0; r < 4; ++r) ss[r] = 0.f;
  const int ntb = 2 * qt + 2;                    // block-uniform suffix tile count
#pragma unroll 1
  for (int tt = z; tt < ntb; tt += KS) {
    if (tt + KS < ntb) STAGE(cur ^ 1, PLEN + (tt + KS) * 32);
    COMPUTE(cur, tt * 32, tt * 32 + 31 > q0);
    __syncthreads();
    cur ^= 1;
  }
  STORE_PHASE(P2buf, S2buf);
}

// combine K-split partials: Ob = g*ΣP1/Σs1 + ΣP2/Σs2
template <int KS>
__global__ __launch_bounds__(256) void k_combine(const __bf16* __restrict__ P1buf,
                                                 const float* __restrict__ S1buf,
                                                 const __bf16* __restrict__ P2buf,
                                                 const float* __restrict__ S2buf,
                                                 const float* __restrict__ gate,
                                                 __bf16* __restrict__ Ob) {
  const int idx = blockIdx.x * 256 + threadIdx.x;  // 16*2048*128 total
  const int d = idx & 127;
  const int q = (idx >> 7) & 2047;
  const int h = idx >> 18;
  const size_t rq = (size_t)h * QLEN + q;
  float a1 = 0.f, a2 = 0.f, s1 = 0.f, s2 = 0.f;
#pragma unroll
  for (int zz = 0; zz < KS; ++zz) {
    const size_t zb = (size_t)zz * NH * QLEN;
    a1 += (float)P1buf[(zb + rq) * HD + d];
    a2 += (float)P2buf[(zb + rq) * HD + d];
    s1 += S1buf[zb + rq];
    s2 += S2buf[zb + rq];
  }
  float o = a1 * (gate[h] / s1) + a2 / s2;
  Ob[(size_t)q * DMODEL + h * HD + d] = (__bf16)o;
}

// ---------------- launch ----------------

extern "C" void kernel_launch(void* const* d_in, const int* in_sizes, int n_in,
                              void* d_out, int out_size, void* d_ws, size_t ws_size,
                              hipStream_t stream) {
  const float* x    = (const float*)d_in[0];
  const float* pk   = (const float*)d_in[1];
  const float* pv   = (const float*)d_in[2];
  const float* Wq   = (const float*)d_in[3];
  const float* bq   = (const float*)d_in[4];
  const float* Wk   = (const float*)d_in[5];
  const float* bk   = (const float*)d_in[6];
  const float* Wv   = (const float*)d_in[7];
  const float* bv   = (const float*)d_in[8];
  const float* gate = (const float*)d_in[9];
  const float* Wout = (const float*)d_in[10];
  const float* bout = (const float*)d_in[11];
  float* out = (float*)d_out;

  char* ws = (char*)d_ws;
  size_t off = 0;
  auto alc = [&](size_t bytes) -> char* {
    char* p = ws + off;
    off += bytes;
    off = (off + 255) & ~(size_t)255;
    return p;
  };
  __bf16* xb   = (__bf16*)alc((size_t)DMODEL * DMODEL * 2);
  __bf16* WqT  = (__bf16*)alc((size_t)DMODEL * DMODEL * 2);
  __bf16* WkT  = (__bf16*)alc((size_t)DMODEL * DMODEL * 2);
  __bf16* WvT  = (__bf16*)alc((size_t)DMODEL * DMODEL * 2);
  __bf16* WoT  = (__bf16*)alc((size_t)DMODEL * DMODEL * 2);
  __bf16* Qs   = (__bf16*)alc((size_t)NH * QLEN * HD * 2);
  __bf16* Kall = (__bf16*)alc((size_t)NH * KVLEN * HD * 2);
  __bf16* VTa  = (__bf16*)alc((size_t)NH * HD * KVLEN * 2);
  __bf16* Ob   = (__bf16*)alc((size_t)QLEN * DMODEL * 2);

  // K-split partial buffers; pick KS=2 if it fits, else KS=1 (deterministic in ws_size)
  const size_t per_split = (size_t)NH * QLEN * HD * 2 * 2   // P1+P2 bf16
                         + (size_t)NH * QLEN * 4 * 2 + 1024; // S1+S2 f32 + align slack
  int KS = (off + 2 * per_split <= ws_size) ? 2 : 1;
  __bf16* P1buf = (__bf16*)alc((size_t)KS * NH * QLEN * HD * 2);
  __bf16* P2buf = (__bf16*)alc((size_t)KS * NH * QLEN * HD * 2);
  float*  S1buf = (float*)alc((size_t)KS * NH * QLEN * 4);
  float*  S2buf = (float*)alc((size_t)KS * NH * QLEN * 4);

  k_transpose4<<<dim3(32, 32, 4), 256, 0, stream>>>(Wq, Wk, Wv, Wout, WqT, WkT, WvT, WoT);
  k_f32_to_bf16<<<1024, 256, 0, stream>>>(x, xb, (DMODEL * DMODEL) / 4);
  k_prefix<<<4096, 256, 0, stream>>>(pk, pv, Kall, VTa);

  gemm_qkv<<<dim3(16, 16, 3), 256, 0, stream>>>(xb, WqT, WkT, WvT, bq, bk, bv, Qs, Kall, VTa);

  const int ncomb = (NH * QLEN * HD) / 256;
  if (KS == 2) {
    k_attn<2><<<1024, 256, 0, stream>>>(Qs, Kall, VTa, P1buf, S1buf, P2buf, S2buf);
    k_combine<2><<<ncomb, 256, 0, stream>>>(P1buf, S1buf, P2buf, S2buf, gate, Ob);
  } else {
    k_attn<1><<<512, 256, 0, stream>>>(Qs, Kall, VTa, P1buf, S1buf, P2buf, S2buf);
    k_combine<1><<<ncomb, 256, 0, stream>>>(P1buf, S1buf, P2buf, S2buf, gate, Ob);
  }
  gemm_out<<<dim3(16, 32), 256, 0, stream>>>(Ob, WoT, bout, out);
}

// Round 8
// 194.322 us; speedup vs baseline: 1.2539x; 1.0034x over previous
//
#include <hip/hip_runtime.h>
#include <hip/hip_bf16.h>

typedef __bf16 bf16x8 __attribute__((ext_vector_type(8)));
typedef __bf16 bf16x4v __attribute__((ext_vector_type(4)));
typedef float f32x4 __attribute__((ext_vector_type(4)));

#define DMODEL 2048
#define NH 16
#define HD 128
#define PLEN 512
#define QLEN 2048
#define KVLEN 2560

__device__ __forceinline__ void gload_lds16(const void* g, void* l) {
  __builtin_amdgcn_global_load_lds((const __attribute__((address_space(1))) void*)g,
                                   (__attribute__((address_space(3))) void*)l, 16, 0, 0);
}

__device__ __forceinline__ unsigned cvt_pk_bf16(float lo, float hi) {
  unsigned r;
  asm volatile("v_cvt_pk_bf16_f32 %0, %1, %2" : "=v"(r) : "v"(lo), "v"(hi));
  return r;
}

// ---------------- fused prep kernel ----------------
// grid (32,32,6): z<4 -> transpose weight z to bf16; z=4 -> x convert to bf16;
// z=5 -> prefix K/V scatter to concat layouts.
__global__ __launch_bounds__(256) void k_prep(const float* __restrict__ Wq,
                                              const float* __restrict__ Wk,
                                              const float* __restrict__ Wv,
                                              const float* __restrict__ Wo,
                                              const float* __restrict__ x,
                                              const float* __restrict__ pk,
                                              const float* __restrict__ pv,
                                              __bf16* __restrict__ WqT,
                                              __bf16* __restrict__ WkT,
                                              __bf16* __restrict__ WvT,
                                              __bf16* __restrict__ WoT,
                                              __bf16* __restrict__ xb,
                                              __bf16* __restrict__ Kall,
                                              __bf16* __restrict__ VT) {
  __shared__ float tile[64][65];
  const int z = blockIdx.z;
  const int t = threadIdx.x;
  const int tx = t & 63, ty = t >> 6;
  if (z < 4) {
    const float* in = (z == 0) ? Wq : (z == 1) ? Wk : (z == 2) ? Wv : Wo;
    __bf16* out = (z == 0) ? WqT : (z == 1) ? WkT : (z == 2) ? WvT : WoT;
    const int r0 = blockIdx.y * 64, c0 = blockIdx.x * 64;
#pragma unroll
    for (int i = 0; i < 16; ++i) {
      int r = ty + i * 4;
      tile[r][tx] = in[(size_t)(r0 + r) * DMODEL + c0 + tx];
    }
    __syncthreads();
#pragma unroll
    for (int i = 0; i < 16; ++i) {
      int r = ty + i * 4;
      out[(size_t)(c0 + r) * DMODEL + r0 + tx] = (__bf16)tile[tx][r];
    }
  } else if (z == 4) {
    const int r0 = blockIdx.y * 64, c0 = blockIdx.x * 64;
#pragma unroll
    for (int i = 0; i < 16; ++i) {
      int r = ty + i * 4;
      xb[(size_t)(r0 + r) * DMODEL + c0 + tx] = (__bf16)x[(size_t)(r0 + r) * DMODEL + c0 + tx];
    }
  } else {
    const int blk = blockIdx.y * 32 + blockIdx.x;  // 0..1023
#pragma unroll
    for (int i = 0; i < 4; ++i) {
      int idx = blk * 1024 + i * 256 + t;          // 0..1048575
      int hd = idx & 127;
      int hh = (idx >> 7) & 15;
      int p = idx >> 11;
      Kall[(size_t)hh * KVLEN * HD + (size_t)p * HD + hd] = (__bf16)pk[idx];
      VT[(size_t)hh * HD * KVLEN + (size_t)hd * KVLEN + p] = (__bf16)pv[idx];
    }
  }
}

// ---------------- GEMM: C[128 x BN] = A[M,K] * BT[N,K]^T, double-buffered ----------------
// (round-4 proven structure: 2-buf, __syncthreads, setprio on MFMA cluster)

template <int BN>
__device__ __forceinline__ void stage_tile(const __bf16* __restrict__ A,
                                           const __bf16* __restrict__ BT,
                                           char* AsmB, char* BsmB,
                                           int m0, int n0, int k0, int w, int l) {
#pragma unroll
  for (int i = 0; i < 2; ++i) {  // A: 128x32 bf16 = 8KB
    int base = i * 4096 + w * 1024;
    int o = base + l * 16;
    int row = o >> 6, col = (o & 63) >> 1;
    gload_lds16(A + (size_t)(m0 + row) * DMODEL + k0 + col, AsmB + base);
  }
  if constexpr (BN == 128) {
#pragma unroll
    for (int i = 0; i < 2; ++i) {
      int base = i * 4096 + w * 1024;
      int o = base + l * 16;
      int row = o >> 6, col = (o & 63) >> 1;
      gload_lds16(BT + (size_t)(n0 + row) * DMODEL + k0 + col, BsmB + base);
    }
  } else {  // BN==64: 4KB
    int base = w * 1024;
    int o = base + l * 16;
    int row = o >> 6, col = (o & 63) >> 1;
    gload_lds16(BT + (size_t)(n0 + row) * DMODEL + k0 + col, BsmB + base);
  }
}

template <int BN>
__device__ __forceinline__ void gemm_mainloop_db(const __bf16* __restrict__ A,
                                                 const __bf16* __restrict__ BT,
                                                 __bf16* Asm, __bf16* Bsm,  // [2][...]
                                                 int m0, int n0, int w, int l,
                                                 f32x4 (&acc)[4][BN / 32]) {
  constexpr int NI = BN / 32;
  constexpr int ABUF = 4096;
  constexpr int BBUF = BN * 32;
  const int lr = l & 15, lg = l >> 4;
  int cur = 0;
  stage_tile<BN>(A, BT, (char*)Asm, (char*)Bsm, m0, n0, 0, w, l);
  __syncthreads();
  for (int k0 = 0; k0 < DMODEL; k0 += 32) {
    if (k0 + 32 < DMODEL)
      stage_tile<BN>(A, BT, (char*)(Asm + (cur ^ 1) * ABUF), (char*)(Bsm + (cur ^ 1) * BBUF),
                     m0, n0, k0 + 32, w, l);
    const __bf16* Ab = Asm + cur * ABUF;
    const __bf16* Bb = Bsm + cur * BBUF;
    bf16x8 af[4], bfv[NI];
#pragma unroll
    for (int mi = 0; mi < 4; ++mi)
      af[mi] = *(const bf16x8*)(Ab + ((w >> 1) * 64 + mi * 16 + lr) * 32 + lg * 8);
#pragma unroll
    for (int ni = 0; ni < NI; ++ni)
      bfv[ni] = *(const bf16x8*)(Bb + ((w & 1) * (BN / 2) + ni * 16 + lr) * 32 + lg * 8);
    __builtin_amdgcn_s_setprio(1);
#pragma unroll
    for (int mi = 0; mi < 4; ++mi)
#pragma unroll
      for (int ni = 0; ni < NI; ++ni)
        acc[mi][ni] = __builtin_amdgcn_mfma_f32_16x16x32_bf16(af[mi], bfv[ni], acc[mi][ni], 0, 0, 0);
    __builtin_amdgcn_s_setprio(0);
    __syncthreads();
    cur ^= 1;
  }
}

// z=0: Q (scaled 1/sqrt(128)) -> Qs[h][q][hd]; z=1: K -> Kall[h][512+q][hd]; z=2: V -> VT[h][hd][512+q]
__global__ __launch_bounds__(256) void gemm_qkv(const __bf16* __restrict__ xb,
                                                const __bf16* __restrict__ WqT,
                                                const __bf16* __restrict__ WkT,
                                                const __bf16* __restrict__ WvT,
                                                const float* __restrict__ bq,
                                                const float* __restrict__ bk,
                                                const float* __restrict__ bv,
                                                __bf16* __restrict__ Qs,
                                                __bf16* __restrict__ Kall,
                                                __bf16* __restrict__ VT) {
  __shared__ __bf16 Asm[2][4096];
  __shared__ __bf16 Bsm[2][4096];
  const int t = threadIdx.x, w = t >> 6, l = t & 63;
  const int m0 = blockIdx.x * 128, n0 = blockIdx.y * 128;
  const int z = blockIdx.z;
  const __bf16* BT = (z == 0) ? WqT : ((z == 1) ? WkT : WvT);
  const float* bias = (z == 0) ? bq : ((z == 1) ? bk : bv);
  f32x4 acc[4][4];
#pragma unroll
  for (int mi = 0; mi < 4; ++mi)
#pragma unroll
    for (int ni = 0; ni < 4; ++ni) acc[mi][ni] = (f32x4){0.f, 0.f, 0.f, 0.f};
  gemm_mainloop_db<128>(xb, BT, &Asm[0][0], &Bsm[0][0], m0, n0, w, l, acc);
  const int lr = l & 15, lg = l >> 4;
#pragma unroll
  for (int mi = 0; mi < 4; ++mi)
#pragma unroll
    for (int ni = 0; ni < 4; ++ni)
#pragma unroll
      for (int r = 0; r < 4; ++r) {
        int row = m0 + (w >> 1) * 64 + mi * 16 + lg * 4 + r;
        int col = n0 + (w & 1) * 64 + ni * 16 + lr;
        float v = acc[mi][ni][r] + bias[col];
        int hh = col >> 7, hd = col & 127;
        if (z == 0) {
          Qs[(size_t)hh * QLEN * HD + (size_t)row * HD + hd] = (__bf16)(v * 0.08838834764831845f);
        } else if (z == 1) {
          Kall[(size_t)hh * KVLEN * HD + (size_t)(PLEN + row) * HD + hd] = (__bf16)v;
        } else {
          VT[(size_t)hh * HD * KVLEN + (size_t)hd * KVLEN + (PLEN + row)] = (__bf16)v;
        }
      }
}

// final: out[q][d] = O[q][:] . WoT[d][:] + bout[d]  (f32 out).  128x64 tiles, 512 blocks.
__global__ __launch_bounds__(256) void gemm_out(const __bf16* __restrict__ Ob,
                                                const __bf16* __restrict__ WoT,
                                                const float* __restrict__ bout,
                                                float* __restrict__ out) {
  __shared__ __bf16 Asm[2][4096];
  __shared__ __bf16 Bsm[2][2048];
  const int t = threadIdx.x, w = t >> 6, l = t & 63;
  const int m0 = blockIdx.x * 128, n0 = blockIdx.y * 64;
  f32x4 acc[4][2];
#pragma unroll
  for (int mi = 0; mi < 4; ++mi)
#pragma unroll
    for (int ni = 0; ni < 2; ++ni) acc[mi][ni] = (f32x4){0.f, 0.f, 0.f, 0.f};
  gemm_mainloop_db<64>(Ob, WoT, &Asm[0][0], &Bsm[0][0], m0, n0, w, l, acc);
  const int lr = l & 15, lg = l >> 4;
#pragma unroll
  for (int mi = 0; mi < 4; ++mi)
#pragma unroll
    for (int ni = 0; ni < 2; ++ni)
#pragma unroll
      for (int r = 0; r < 4; ++r) {
        int row = m0 + (w >> 1) * 64 + mi * 16 + lg * 4 + r;
        int col = n0 + (w & 1) * 32 + ni * 16 + lr;
        out[(size_t)row * DMODEL + col] = acc[mi][ni][r] + bout[col];
      }
}

// ---------------- attention (balanced K-split + swapped-QK in-register P) ----------------
// Work mapping (proven r7): flat grid 512*KS; b=id&255, k=id>>8, h=b>>4, m=b&15;
// KS=2: z=k>>1, j=2m+(k>>1), qt=(k&1)?31-j:j — bijective; the 4 blocks a CU receives
// under round-robin {c,c+256,c+512,c+768} have suffix tile counts summing to a constant.
// Swapped QK^T (T12): compute mfma(K,Q) so lane l holds P[k=4*lg+r (+16)][q=lr] —
// P reaches PV's A-operand via 4 cvt_pk + 8 shfl (no LDS round-trip, no P buffer).
// Fixed-max softmax exp(S-16) (|logit|<=~12 by Cauchy-Schwarz; masked lanes exp->0).
template <int KS>
__global__ __launch_bounds__(256, 4) void k_attn(const __bf16* __restrict__ Qs,
                                                 const __bf16* __restrict__ Kall,
                                                 const __bf16* __restrict__ VT,
                                                 __bf16* __restrict__ P1buf,
                                                 float* __restrict__ S1buf,
                                                 __bf16* __restrict__ P2buf,
                                                 float* __restrict__ S2buf) {
  __shared__ __bf16 Ksm[2][4096];   // [buf][32 kv][128 hd] (xor-swizzled)
  __shared__ __bf16 Vsm[2][4096];   // [buf][128 hd][32 kv] (xor-swizzled)
  const int id = blockIdx.x;
  const int b = id & 255, k = id >> 8;
  const int h = b >> 4, m = b & 15;
  int qt, z;
  if constexpr (KS == 2) {
    z = k >> 1;
    const int j = 2 * m + (k >> 1);
    qt = (k & 1) ? (31 - j) : j;
  } else {
    z = 0;
    qt = (k & 1) ? (31 - 2 * m) : (2 * m);
  }
  const int t = threadIdx.x, w = t >> 6, l = t & 63;
  const int lr = l & 15, lg = l >> 4;
  const int q0 = qt * 64 + w * 16;
  const __bf16* Qh = Qs + (size_t)h * QLEN * HD;
  const char* Khb = (const char*)(Kall + (size_t)h * KVLEN * HD);
  const char* Vhb = (const char*)(VT + (size_t)h * HD * KVLEN);

  bf16x8 qf[4];
#pragma unroll
  for (int c = 0; c < 4; ++c)
    qf[c] = *(const bf16x8*)(Qh + (size_t)(q0 + lr) * HD + c * 32 + lg * 8);

  f32x4 acc[8];
  float ss;

  // stage 32-key tile (keys kb..kb+31) into buffer `buf`
  auto STAGE = [&](int buf, int kb) {
#pragma unroll
    for (int i = 0; i < 2; ++i) {  // K: 8KB, rows contiguous in global
      int o = (i * 256 + w * 64 + l) * 16;
      int po = o ^ (((o >> 8) & 7) << 4);
      gload_lds16(Khb + (size_t)kb * 256 + po, (char*)&Ksm[buf][0] + i * 4096 + w * 1024);
    }
#pragma unroll
    for (int i = 0; i < 2; ++i) {  // V: 8KB, rows strided KVLEN*2 in global VT
      int o = (i * 256 + w * 64 + l) * 16;
      int po = o ^ (((o >> 7) & 7) << 4);
      int row = po >> 6, colb = po & 63;
      gload_lds16(Vhb + (size_t)row * (KVLEN * 2) + (size_t)kb * 2 + colb,
                  (char*)&Vsm[buf][0] + i * 4096 + w * 1024);
    }
  };

  // compute one staged tile; mrel = suffix-relative key base (only used if domask)
  auto COMPUTE = [&](int buf, int mrel, bool domask) {
    const char* Kb = (const char*)&Ksm[buf][0];
    const char* Vb = (const char*)&Vsm[buf][0];
    f32x4 st0 = {0.f, 0.f, 0.f, 0.f}, st1 = {0.f, 0.f, 0.f, 0.f};
    __builtin_amdgcn_s_setprio(1);
#pragma unroll
    for (int c = 0; c < 4; ++c) {
      int o0 = lr * 256 + c * 64 + lg * 16;        o0 ^= ((o0 >> 8) & 7) << 4;
      int o1 = (16 + lr) * 256 + c * 64 + lg * 16; o1 ^= ((o1 >> 8) & 7) << 4;
      bf16x8 kf0 = *(const bf16x8*)(Kb + o0);
      bf16x8 kf1 = *(const bf16x8*)(Kb + o1);
      // SWAPPED: A=K (rows = key), B=Q (rows = q) -> P[k][q], q = lane&15
      st0 = __builtin_amdgcn_mfma_f32_16x16x32_bf16(kf0, qf[c], st0, 0, 0, 0);
      st1 = __builtin_amdgcn_mfma_f32_16x16x32_bf16(kf1, qf[c], st1, 0, 0, 0);
    }
    __builtin_amdgcn_s_setprio(0);
    const int qabs = q0 + lr;
    float e0[4], e1[4];
    float ps = 0.f;
#pragma unroll
    for (int r = 0; r < 4; ++r) {
      e0[r] = __expf(st0[r] - 16.0f);
      e1[r] = __expf(st1[r] - 16.0f);
      if (domask) {
        if (mrel + 4 * lg + r > qabs) e0[r] = 0.f;
        if (mrel + 16 + 4 * lg + r > qabs) e1[r] = 0.f;
      }
      ps += e0[r] + e1[r];
    }
    ss += ps;
    // pack P -> bf16 words: W0={k:4lg,4lg+1} W1={4lg+2,4lg+3} W2={16+4lg,..} W3
    unsigned W0 = cvt_pk_bf16(e0[0], e0[1]);
    unsigned W1 = cvt_pk_bf16(e0[2], e0[3]);
    unsigned W2 = cvt_pk_bf16(e1[0], e1[1]);
    unsigned W3 = cvt_pk_bf16(e1[2], e1[3]);
    // redistribute: target lane-group g needs k=8g..8g+7
    const int srcA = lr + (((2 * lg) & 3) << 4);
    const int srcB = lr + (((2 * lg + 1) & 3) << 4);
    unsigned A0 = __shfl(W0, srcA), A1 = __shfl(W1, srcA);
    unsigned A2 = __shfl(W0, srcB), A3 = __shfl(W1, srcB);
    unsigned B0 = __shfl(W2, srcA), B1 = __shfl(W3, srcA);
    unsigned B2 = __shfl(W2, srcB), B3 = __shfl(W3, srcB);
    union { unsigned u[4]; bf16x8 v; } pu;
    pu.u[0] = (lg < 2) ? A0 : B0;
    pu.u[1] = (lg < 2) ? A1 : B1;
    pu.u[2] = (lg < 2) ? A2 : B2;
    pu.u[3] = (lg < 2) ? A3 : B3;
    bf16x8 pf = pu.v;
    __builtin_amdgcn_s_setprio(1);
#pragma unroll
    for (int c = 0; c < 8; ++c) {
      int o = (c * 16 + lr) * 64 + lg * 16; o ^= ((o >> 7) & 7) << 4;
      bf16x8 vf = *(const bf16x8*)(Vb + o);
      acc[c] = __builtin_amdgcn_mfma_f32_16x16x32_bf16(pf, vf, acc[c], 0, 0, 0);
    }
    __builtin_amdgcn_s_setprio(0);
  };

  auto STORE_PHASE = [&](__bf16* PBUF, float* SBUF) {
    const size_t rb = (size_t)(z * NH + h) * QLEN;
    float s = ss;
    s += __shfl_xor(s, 16);
    s += __shfl_xor(s, 32);
    if (l < 16) SBUF[rb + q0 + l] = s;
#pragma unroll
    for (int r = 0; r < 4; ++r) {
      const int row = q0 + lg * 4 + r;
#pragma unroll
      for (int c = 0; c < 8; ++c)
        PBUF[(rb + row) * HD + c * 16 + lr] = (__bf16)acc[c][r];
    }
  };

  // ---- phase 1: prefix, tiles tt ≡ z (mod KS), tt < 16, unmasked ----
#pragma unroll
  for (int c = 0; c < 8; ++c) acc[c] = (f32x4){0.f, 0.f, 0.f, 0.f};
  ss = 0.f;
  int cur = 0;
  STAGE(0, z * 32);
  __syncthreads();
#pragma unroll 1
  for (int tt = z; tt < 16; tt += KS) {
    if (tt + KS < 16) STAGE(cur ^ 1, (tt + KS) * 32);
    else STAGE(cur ^ 1, PLEN + z * 32);          // phase-2 prologue
    COMPUTE(cur, 0, false);
    __syncthreads();
    cur ^= 1;
  }
  STORE_PHASE(P1buf, S1buf);

  // ---- phase 2: causal suffix (buffer `cur` already staged) ----
#pragma unroll
  for (int c = 0; c < 8; ++c) acc[c] = (f32x4){0.f, 0.f, 0.f, 0.f};
  ss = 0.f;
  const int ntb = 2 * qt + 2;                    // block-uniform suffix tile count
#pragma unroll 1
  for (int tt = z; tt < ntb; tt += KS) {
    if (tt + KS < ntb) STAGE(cur ^ 1, PLEN + (tt + KS) * 32);
    COMPUTE(cur, tt * 32, tt * 32 + 31 > q0);
    __syncthreads();
    cur ^= 1;
  }
  STORE_PHASE(P2buf, S2buf);
}

// combine K-split partials: Ob = g*ΣP1/Σs1 + ΣP2/Σs2
template <int KS>
__global__ __launch_bounds__(256) void k_combine(const __bf16* __restrict__ P1buf,
                                                 const float* __restrict__ S1buf,
                                                 const __bf16* __restrict__ P2buf,
                                                 const float* __restrict__ S2buf,
                                                 const float* __restrict__ gate,
                                                 __bf16* __restrict__ Ob) {
  const int idx = blockIdx.x * 256 + threadIdx.x;  // 16*2048*128 total
  const int d = idx & 127;
  const int q = (idx >> 7) & 2047;
  const int h = idx >> 18;
  const size_t rq = (size_t)h * QLEN + q;
  float a1 = 0.f, a2 = 0.f, s1 = 0.f, s2 = 0.f;
#pragma unroll
  for (int zz = 0; zz < KS; ++zz) {
    const size_t zb = (size_t)zz * NH * QLEN;
    a1 += (float)P1buf[(zb + rq) * HD + d];
    a2 += (float)P2buf[(zb + rq) * HD + d];
    s1 += S1buf[zb + rq];
    s2 += S2buf[zb + rq];
  }
  float o = a1 * (gate[h] / s1) + a2 / s2;
  Ob[(size_t)q * DMODEL + h * HD + d] = (__bf16)o;
}

// ---------------- launch ----------------

extern "C" void kernel_launch(void* const* d_in, const int* in_sizes, int n_in,
                              void* d_out, int out_size, void* d_ws, size_t ws_size,
                              hipStream_t stream) {
  const float* x    = (const float*)d_in[0];
  const float* pk   = (const float*)d_in[1];
  const float* pv   = (const float*)d_in[2];
  const float* Wq   = (const float*)d_in[3];
  const float* bq   = (const float*)d_in[4];
  const float* Wk   = (const float*)d_in[5];
  const float* bk   = (const float*)d_in[6];
  const float* Wv   = (const float*)d_in[7];
  const float* bv   = (const float*)d_in[8];
  const float* gate = (const float*)d_in[9];
  const float* Wout = (const float*)d_in[10];
  const float* bout = (const float*)d_in[11];
  float* out = (float*)d_out;

  char* ws = (char*)d_ws;
  size_t off = 0;
  auto alc = [&](size_t bytes) -> char* {
    char* p = ws + off;
    off += bytes;
    off = (off + 255) & ~(size_t)255;
    return p;
  };
  __bf16* xb   = (__bf16*)alc((size_t)DMODEL * DMODEL * 2);
  __bf16* WqT  = (__bf16*)alc((size_t)DMODEL * DMODEL * 2);
  __bf16* WkT  = (__bf16*)alc((size_t)DMODEL * DMODEL * 2);
  __bf16* WvT  = (__bf16*)alc((size_t)DMODEL * DMODEL * 2);
  __bf16* WoT  = (__bf16*)alc((size_t)DMODEL * DMODEL * 2);
  __bf16* Qs   = (__bf16*)alc((size_t)NH * QLEN * HD * 2);
  __bf16* Kall = (__bf16*)alc((size_t)NH * KVLEN * HD * 2);
  __bf16* VTa  = (__bf16*)alc((size_t)NH * HD * KVLEN * 2);
  __bf16* Ob   = (__bf16*)alc((size_t)QLEN * DMODEL * 2);

  // K-split partial buffers; pick KS=2 if it fits, else KS=1 (deterministic in ws_size)
  const size_t per_split = (size_t)NH * QLEN * HD * 2 * 2   // P1+P2 bf16
                         + (size_t)NH * QLEN * 4 * 2 + 1024; // S1+S2 f32 + align slack
  int KS = (off + 2 * per_split <= ws_size) ? 2 : 1;
  __bf16* P1buf = (__bf16*)alc((size_t)KS * NH * QLEN * HD * 2);
  __bf16* P2buf = (__bf16*)alc((size_t)KS * NH * QLEN * HD * 2);
  float*  S1buf = (float*)alc((size_t)KS * NH * QLEN * 4);
  float*  S2buf = (float*)alc((size_t)KS * NH * QLEN * 4);

  k_prep<<<dim3(32, 32, 6), 256, 0, stream>>>(Wq, Wk, Wv, Wout, x, pk, pv,
                                              WqT, WkT, WvT, WoT, xb, Kall, VTa);

  gemm_qkv<<<dim3(16, 16, 3), 256, 0, stream>>>(xb, WqT, WkT, WvT, bq, bk, bv, Qs, Kall, VTa);

  const int ncomb = (NH * QLEN * HD) / 256;
  if (KS == 2) {
    k_attn<2><<<1024, 256, 0, stream>>>(Qs, Kall, VTa, P1buf, S1buf, P2buf, S2buf);
    k_combine<2><<<ncomb, 256, 0, stream>>>(P1buf, S1buf, P2buf, S2buf, gate, Ob);
  } else {
    k_attn<1><<<512, 256, 0, stream>>>(Qs, Kall, VTa, P1buf, S1buf, P2buf, S2buf);
    k_combine<1><<<ncomb, 256, 0, stream>>>(P1buf, S1buf, P2buf, S2buf, gate, Ob);
  }
  gemm_out<<<dim3(16, 32), 256, 0, stream>>>(Ob, WoT, bout, out);
}

// Round 9
// 191.431 us; speedup vs baseline: 1.2728x; 1.0151x over previous
//
#include <hip/hip_runtime.h>
#include <hip/hip_bf16.h>

typedef __bf16 bf16x8 __attribute__((ext_vector_type(8)));
typedef __bf16 bf16x4v __attribute__((ext_vector_type(4)));
typedef float f32x4 __attribute__((ext_vector_type(4)));

#define DMODEL 2048
#define NH 16
#define HD 128
#define PLEN 512
#define QLEN 2048
#define KVLEN 2560

__device__ __forceinline__ void gload_lds16(const void* g, void* l) {
  __builtin_amdgcn_global_load_lds((const __attribute__((address_space(1))) void*)g,
                                   (__attribute__((address_space(3))) void*)l, 16, 0, 0);
}

__device__ __forceinline__ unsigned cvt_pk_bf16(float lo, float hi) {
  unsigned r;
  asm volatile("v_cvt_pk_bf16_f32 %0, %1, %2" : "=v"(r) : "v"(lo), "v"(hi));
  return r;
}

// ---------------- fused prep kernel ----------------
// grid (32,32,7): z<4 -> transpose weight z to bf16; z=4 -> x convert;
// z=5 -> prefix K copy (coalesced); z=6 -> prefix V transpose via LDS (coalesced).
__global__ __launch_bounds__(256) void k_prep(const float* __restrict__ Wq,
                                              const float* __restrict__ Wk,
                                              const float* __restrict__ Wv,
                                              const float* __restrict__ Wo,
                                              const float* __restrict__ x,
                                              const float* __restrict__ pk,
                                              const float* __restrict__ pv,
                                              __bf16* __restrict__ WqT,
                                              __bf16* __restrict__ WkT,
                                              __bf16* __restrict__ WvT,
                                              __bf16* __restrict__ WoT,
                                              __bf16* __restrict__ xb,
                                              __bf16* __restrict__ Kall,
                                              __bf16* __restrict__ VT) {
  __shared__ float tile[64][65];          // z<4 transpose staging
  __shared__ __bf16 Vt[128][66];          // z=6: [hd][64 p + 2 pad]
  const int z = blockIdx.z;
  const int t = threadIdx.x;
  const int tx = t & 63, ty = t >> 6;
  if (z < 4) {
    const float* in = (z == 0) ? Wq : (z == 1) ? Wk : (z == 2) ? Wv : Wo;
    __bf16* out = (z == 0) ? WqT : (z == 1) ? WkT : (z == 2) ? WvT : WoT;
    const int r0 = blockIdx.y * 64, c0 = blockIdx.x * 64;
#pragma unroll
    for (int i = 0; i < 16; ++i) {
      int r = ty + i * 4;
      tile[r][tx] = in[(size_t)(r0 + r) * DMODEL + c0 + tx];
    }
    __syncthreads();
#pragma unroll
    for (int i = 0; i < 16; ++i) {
      int r = ty + i * 4;
      out[(size_t)(c0 + r) * DMODEL + r0 + tx] = (__bf16)tile[tx][r];
    }
  } else if (z == 4) {
    const int r0 = blockIdx.y * 64, c0 = blockIdx.x * 64;
#pragma unroll
    for (int i = 0; i < 16; ++i) {
      int r = ty + i * 4;
      xb[(size_t)(r0 + r) * DMODEL + c0 + tx] = (__bf16)x[(size_t)(r0 + r) * DMODEL + c0 + tx];
    }
  } else if (z == 5) {
    const int blk = blockIdx.y * 32 + blockIdx.x;  // 0..1023
#pragma unroll
    for (int i = 0; i < 4; ++i) {
      int idx = blk * 1024 + i * 256 + t;          // 0..1048575
      int hd = idx & 127;
      int hh = (idx >> 7) & 15;
      int p = idx >> 11;
      Kall[(size_t)hh * KVLEN * HD + (size_t)p * HD + hd] = (__bf16)pk[idx];
    }
  } else {
    const int b = blockIdx.y * 32 + blockIdx.x;    // need 128 blocks
    if (b >= 128) return;
    const int h = b >> 3;
    const int p0 = (b & 7) * 64;
    // read pv[p0+p][h][hd] coalesced, write Vt[hd][p] (transposed, padded)
#pragma unroll
    for (int i = 0; i < 32; ++i) {
      int idx = i * 256 + t;       // 8192 = 64 p x 128 hd
      int hd = idx & 127;
      int p = idx >> 7;
      Vt[hd][p] = (__bf16)pv[(size_t)(p0 + p) * DMODEL + h * HD + hd];
    }
    __syncthreads();
    // write VT[h][hd][p0..p0+63]: wave handles hd rows, lanes pack p-pairs (4B)
    const int wv = t >> 6, l = t & 63;
    const int lp = l & 31;          // p-pair index (two waves-halves duplicate guard)
    if (l < 32) {
#pragma unroll
      for (int j = 0; j < 32; ++j) {
        int hd = wv * 32 + j;
        unsigned u = *(const unsigned*)&Vt[hd][2 * lp];
        *(unsigned*)(VT + (size_t)h * HD * KVLEN + (size_t)hd * KVLEN + p0 + 2 * lp) = u;
      }
    }
  }
}

// ---------------- GEMM: C[128 x BN] = A[M,K] * BT[N,K]^T, double-buffered ----------------
// (round-4 proven structure: 2-buf, __syncthreads, setprio on MFMA cluster)

template <int BN>
__device__ __forceinline__ void stage_tile(const __bf16* __restrict__ A,
                                           const __bf16* __restrict__ BT,
                                           char* AsmB, char* BsmB,
                                           int m0, int n0, int k0, int w, int l) {
#pragma unroll
  for (int i = 0; i < 2; ++i) {  // A: 128x32 bf16 = 8KB
    int base = i * 4096 + w * 1024;
    int o = base + l * 16;
    int row = o >> 6, col = (o & 63) >> 1;
    gload_lds16(A + (size_t)(m0 + row) * DMODEL + k0 + col, AsmB + base);
  }
  if constexpr (BN == 128) {
#pragma unroll
    for (int i = 0; i < 2; ++i) {
      int base = i * 4096 + w * 1024;
      int o = base + l * 16;
      int row = o >> 6, col = (o & 63) >> 1;
      gload_lds16(BT + (size_t)(n0 + row) * DMODEL + k0 + col, BsmB + base);
    }
  } else {  // BN==64: 4KB
    int base = w * 1024;
    int o = base + l * 16;
    int row = o >> 6, col = (o & 63) >> 1;
    gload_lds16(BT + (size_t)(n0 + row) * DMODEL + k0 + col, BsmB + base);
  }
}

template <int BN>
__device__ __forceinline__ void gemm_mainloop_db(const __bf16* __restrict__ A,
                                                 const __bf16* __restrict__ BT,
                                                 __bf16* Asm, __bf16* Bsm,  // [2][...]
                                                 int m0, int n0, int w, int l,
                                                 f32x4 (&acc)[4][BN / 32]) {
  constexpr int NI = BN / 32;
  constexpr int ABUF = 4096;
  constexpr int BBUF = BN * 32;
  const int lr = l & 15, lg = l >> 4;
  int cur = 0;
  stage_tile<BN>(A, BT, (char*)Asm, (char*)Bsm, m0, n0, 0, w, l);
  __syncthreads();
  for (int k0 = 0; k0 < DMODEL; k0 += 32) {
    if (k0 + 32 < DMODEL)
      stage_tile<BN>(A, BT, (char*)(Asm + (cur ^ 1) * ABUF), (char*)(Bsm + (cur ^ 1) * BBUF),
                     m0, n0, k0 + 32, w, l);
    const __bf16* Ab = Asm + cur * ABUF;
    const __bf16* Bb = Bsm + cur * BBUF;
    bf16x8 af[4], bfv[NI];
#pragma unroll
    for (int mi = 0; mi < 4; ++mi)
      af[mi] = *(const bf16x8*)(Ab + ((w >> 1) * 64 + mi * 16 + lr) * 32 + lg * 8);
#pragma unroll
    for (int ni = 0; ni < NI; ++ni)
      bfv[ni] = *(const bf16x8*)(Bb + ((w & 1) * (BN / 2) + ni * 16 + lr) * 32 + lg * 8);
    __builtin_amdgcn_s_setprio(1);
#pragma unroll
    for (int mi = 0; mi < 4; ++mi)
#pragma unroll
      for (int ni = 0; ni < NI; ++ni)
        acc[mi][ni] = __builtin_amdgcn_mfma_f32_16x16x32_bf16(af[mi], bfv[ni], acc[mi][ni], 0, 0, 0);
    __builtin_amdgcn_s_setprio(0);
    __syncthreads();
    cur ^= 1;
  }
}

// z=0: Q (scaled) -> Qs[h][q][hd]; z=1: K -> Kall[h][512+q][hd]; z=2: V -> VT[h][hd][512+q]
// z=2 routes through a padded LDS transpose (Csm aliases Asm/Bsm) for coalesced VT stores.
__global__ __launch_bounds__(256) void gemm_qkv(const __bf16* __restrict__ xb,
                                                const __bf16* __restrict__ WqT,
                                                const __bf16* __restrict__ WkT,
                                                const __bf16* __restrict__ WvT,
                                                const float* __restrict__ bq,
                                                const float* __restrict__ bk,
                                                const float* __restrict__ bv,
                                                __bf16* __restrict__ Qs,
                                                __bf16* __restrict__ Kall,
                                                __bf16* __restrict__ VT) {
  __shared__ __bf16 smem[17024];  // Asm: [0,8192), Bsm: [8192,16384); Csm view: [128][132]
  __bf16* Asm = smem;
  __bf16* Bsm = smem + 8192;
  const int t = threadIdx.x, w = t >> 6, l = t & 63;
  const int m0 = blockIdx.x * 128, n0 = blockIdx.y * 128;
  const int z = blockIdx.z;
  const __bf16* BT = (z == 0) ? WqT : ((z == 1) ? WkT : WvT);
  const float* bias = (z == 0) ? bq : ((z == 1) ? bk : bv);
  f32x4 acc[4][4];
#pragma unroll
  for (int mi = 0; mi < 4; ++mi)
#pragma unroll
    for (int ni = 0; ni < 4; ++ni) acc[mi][ni] = (f32x4){0.f, 0.f, 0.f, 0.f};
  gemm_mainloop_db<128>(xb, BT, Asm, Bsm, m0, n0, w, l, acc);
  const int lr = l & 15, lg = l >> 4;
  if (z == 2) {
    // write C into Csm[col][row] (padded stride 132), then coalesced VT stores
#pragma unroll
    for (int mi = 0; mi < 4; ++mi)
#pragma unroll
      for (int ni = 0; ni < 4; ++ni)
#pragma unroll
        for (int r = 0; r < 4; ++r) {
          int row = (w >> 1) * 64 + mi * 16 + lg * 4 + r;
          int col = (w & 1) * 64 + ni * 16 + lr;
          smem[col * 132 + row] = (__bf16)(acc[mi][ni][r] + bias[n0 + col]);
        }
    __syncthreads();
    const int hh = n0 >> 7;
    __bf16* vbase = VT + (size_t)hh * HD * KVLEN + (size_t)(PLEN + m0);
    if (l < 32) {
#pragma unroll
      for (int j = 0; j < 32; ++j) {
        int hd = w * 32 + j;
        unsigned u = *(const unsigned*)&smem[hd * 132 + 2 * l + 64 * (l >> 5)];
        *(unsigned*)(vbase + (size_t)hd * KVLEN + 2 * l) = u;
      }
    } else {
      const int lp = l - 32;
#pragma unroll
      for (int j = 0; j < 32; ++j) {
        int hd = w * 32 + j;
        unsigned u = *(const unsigned*)&smem[hd * 132 + 64 + 2 * lp];
        *(unsigned*)(vbase + (size_t)hd * KVLEN + 64 + 2 * lp) = u;
      }
    }
  } else {
#pragma unroll
    for (int mi = 0; mi < 4; ++mi)
#pragma unroll
      for (int ni = 0; ni < 4; ++ni)
#pragma unroll
        for (int r = 0; r < 4; ++r) {
          int row = m0 + (w >> 1) * 64 + mi * 16 + lg * 4 + r;
          int col = n0 + (w & 1) * 64 + ni * 16 + lr;
          float v = acc[mi][ni][r] + bias[col];
          int hh = col >> 7, hd = col & 127;
          if (z == 0) {
            Qs[(size_t)hh * QLEN * HD + (size_t)row * HD + hd] = (__bf16)(v * 0.08838834764831845f);
          } else {
            Kall[(size_t)hh * KVLEN * HD + (size_t)(PLEN + row) * HD + hd] = (__bf16)v;
          }
        }
  }
}

// final: out[q][d] = O[q][:] . WoT[d][:] + bout[d]  (f32 out).  128x64 tiles, 512 blocks.
__global__ __launch_bounds__(256) void gemm_out(const __bf16* __restrict__ Ob,
                                                const __bf16* __restrict__ WoT,
                                                const float* __restrict__ bout,
                                                float* __restrict__ out) {
  __shared__ __bf16 Asm[2][4096];
  __shared__ __bf16 Bsm[2][2048];
  const int t = threadIdx.x, w = t >> 6, l = t & 63;
  const int m0 = blockIdx.x * 128, n0 = blockIdx.y * 64;
  f32x4 acc[4][2];
#pragma unroll
  for (int mi = 0; mi < 4; ++mi)
#pragma unroll
    for (int ni = 0; ni < 2; ++ni) acc[mi][ni] = (f32x4){0.f, 0.f, 0.f, 0.f};
  gemm_mainloop_db<64>(Ob, WoT, &Asm[0][0], &Bsm[0][0], m0, n0, w, l, acc);
  const int lr = l & 15, lg = l >> 4;
#pragma unroll
  for (int mi = 0; mi < 4; ++mi)
#pragma unroll
    for (int ni = 0; ni < 2; ++ni)
#pragma unroll
      for (int r = 0; r < 4; ++r) {
        int row = m0 + (w >> 1) * 64 + mi * 16 + lg * 4 + r;
        int col = n0 + (w & 1) * 32 + ni * 16 + lr;
        out[(size_t)row * DMODEL + col] = acc[mi][ni][r] + bout[col];
      }
}

// ---------------- attention (balanced K-split + swapped-QK in-register P) ----------------
// (round-8 passing version, unchanged)
template <int KS>
__global__ __launch_bounds__(256, 4) void k_attn(const __bf16* __restrict__ Qs,
                                                 const __bf16* __restrict__ Kall,
                                                 const __bf16* __restrict__ VT,
                                                 __bf16* __restrict__ P1buf,
                                                 float* __restrict__ S1buf,
                                                 __bf16* __restrict__ P2buf,
                                                 float* __restrict__ S2buf) {
  __shared__ __bf16 Ksm[2][4096];   // [buf][32 kv][128 hd] (xor-swizzled)
  __shared__ __bf16 Vsm[2][4096];   // [buf][128 hd][32 kv] (xor-swizzled)
  const int id = blockIdx.x;
  const int b = id & 255, k = id >> 8;
  const int h = b >> 4, m = b & 15;
  int qt, z;
  if constexpr (KS == 2) {
    z = k >> 1;
    const int j = 2 * m + (k >> 1);
    qt = (k & 1) ? (31 - j) : j;
  } else {
    z = 0;
    qt = (k & 1) ? (31 - 2 * m) : (2 * m);
  }
  const int t = threadIdx.x, w = t >> 6, l = t & 63;
  const int lr = l & 15, lg = l >> 4;
  const int q0 = qt * 64 + w * 16;
  const __bf16* Qh = Qs + (size_t)h * QLEN * HD;
  const char* Khb = (const char*)(Kall + (size_t)h * KVLEN * HD);
  const char* Vhb = (const char*)(VT + (size_t)h * HD * KVLEN);

  bf16x8 qf[4];
#pragma unroll
  for (int c = 0; c < 4; ++c)
    qf[c] = *(const bf16x8*)(Qh + (size_t)(q0 + lr) * HD + c * 32 + lg * 8);

  f32x4 acc[8];
  float ss;

  auto STAGE = [&](int buf, int kb) {
#pragma unroll
    for (int i = 0; i < 2; ++i) {  // K: 8KB, rows contiguous in global
      int o = (i * 256 + w * 64 + l) * 16;
      int po = o ^ (((o >> 8) & 7) << 4);
      gload_lds16(Khb + (size_t)kb * 256 + po, (char*)&Ksm[buf][0] + i * 4096 + w * 1024);
    }
#pragma unroll
    for (int i = 0; i < 2; ++i) {  // V: 8KB, rows strided KVLEN*2 in global VT
      int o = (i * 256 + w * 64 + l) * 16;
      int po = o ^ (((o >> 7) & 7) << 4);
      int row = po >> 6, colb = po & 63;
      gload_lds16(Vhb + (size_t)row * (KVLEN * 2) + (size_t)kb * 2 + colb,
                  (char*)&Vsm[buf][0] + i * 4096 + w * 1024);
    }
  };

  auto COMPUTE = [&](int buf, int mrel, bool domask) {
    const char* Kb = (const char*)&Ksm[buf][0];
    const char* Vb = (const char*)&Vsm[buf][0];
    f32x4 st0 = {0.f, 0.f, 0.f, 0.f}, st1 = {0.f, 0.f, 0.f, 0.f};
    __builtin_amdgcn_s_setprio(1);
#pragma unroll
    for (int c = 0; c < 4; ++c) {
      int o0 = lr * 256 + c * 64 + lg * 16;        o0 ^= ((o0 >> 8) & 7) << 4;
      int o1 = (16 + lr) * 256 + c * 64 + lg * 16; o1 ^= ((o1 >> 8) & 7) << 4;
      bf16x8 kf0 = *(const bf16x8*)(Kb + o0);
      bf16x8 kf1 = *(const bf16x8*)(Kb + o1);
      st0 = __builtin_amdgcn_mfma_f32_16x16x32_bf16(kf0, qf[c], st0, 0, 0, 0);
      st1 = __builtin_amdgcn_mfma_f32_16x16x32_bf16(kf1, qf[c], st1, 0, 0, 0);
    }
    __builtin_amdgcn_s_setprio(0);
    const int qabs = q0 + lr;
    float e0[4], e1[4];
    float ps = 0.f;
#pragma unroll
    for (int r = 0; r < 4; ++r) {
      e0[r] = __expf(st0[r] - 16.0f);
      e1[r] = __expf(st1[r] - 16.0f);
      if (domask) {
        if (mrel + 4 * lg + r > qabs) e0[r] = 0.f;
        if (mrel + 16 + 4 * lg + r > qabs) e1[r] = 0.f;
      }
      ps += e0[r] + e1[r];
    }
    ss += ps;
    unsigned W0 = cvt_pk_bf16(e0[0], e0[1]);
    unsigned W1 = cvt_pk_bf16(e0[2], e0[3]);
    unsigned W2 = cvt_pk_bf16(e1[0], e1[1]);
    unsigned W3 = cvt_pk_bf16(e1[2], e1[3]);
    const int srcA = lr + (((2 * lg) & 3) << 4);
    const int srcB = lr + (((2 * lg + 1) & 3) << 4);
    unsigned A0 = __shfl(W0, srcA), A1 = __shfl(W1, srcA);
    unsigned A2 = __shfl(W0, srcB), A3 = __shfl(W1, srcB);
    unsigned B0 = __shfl(W2, srcA), B1 = __shfl(W3, srcA);
    unsigned B2 = __shfl(W2, srcB), B3 = __shfl(W3, srcB);
    union { unsigned u[4]; bf16x8 v; } pu;
    pu.u[0] = (lg < 2) ? A0 : B0;
    pu.u[1] = (lg < 2) ? A1 : B1;
    pu.u[2] = (lg < 2) ? A2 : B2;
    pu.u[3] = (lg < 2) ? A3 : B3;
    bf16x8 pf = pu.v;
    __builtin_amdgcn_s_setprio(1);
#pragma unroll
    for (int c = 0; c < 8; ++c) {
      int o = (c * 16 + lr) * 64 + lg * 16; o ^= ((o >> 7) & 7) << 4;
      bf16x8 vf = *(const bf16x8*)(Vb + o);
      acc[c] = __builtin_amdgcn_mfma_f32_16x16x32_bf16(pf, vf, acc[c], 0, 0, 0);
    }
    __builtin_amdgcn_s_setprio(0);
  };

  auto STORE_PHASE = [&](__bf16* PBUF, float* SBUF) {
    const size_t rb = (size_t)(z * NH + h) * QLEN;
    float s = ss;
    s += __shfl_xor(s, 16);
    s += __shfl_xor(s, 32);
    if (l < 16) SBUF[rb + q0 + l] = s;
#pragma unroll
    for (int r = 0; r < 4; ++r) {
      const int row = q0 + lg * 4 + r;
#pragma unroll
      for (int c = 0; c < 8; ++c)
        PBUF[(rb + row) * HD + c * 16 + lr] = (__bf16)acc[c][r];
    }
  };

#pragma unroll
  for (int c = 0; c < 8; ++c) acc[c] = (f32x4){0.f, 0.f, 0.f, 0.f};
  ss = 0.f;
  int cur = 0;
  STAGE(0, z * 32);
  __syncthreads();
#pragma unroll 1
  for (int tt = z; tt < 16; tt += KS) {
    if (tt + KS < 16) STAGE(cur ^ 1, (tt + KS) * 32);
    else STAGE(cur ^ 1, PLEN + z * 32);
    COMPUTE(cur, 0, false);
    __syncthreads();
    cur ^= 1;
  }
  STORE_PHASE(P1buf, S1buf);

#pragma unroll
  for (int c = 0; c < 8; ++c) acc[c] = (f32x4){0.f, 0.f, 0.f, 0.f};
  ss = 0.f;
  const int ntb = 2 * qt + 2;
#pragma unroll 1
  for (int tt = z; tt < ntb; tt += KS) {
    if (tt + KS < ntb) STAGE(cur ^ 1, PLEN + (tt + KS) * 32);
    COMPUTE(cur, tt * 32, tt * 32 + 31 > q0);
    __syncthreads();
    cur ^= 1;
  }
  STORE_PHASE(P2buf, S2buf);
}

// combine K-split partials: Ob = g*ΣP1/Σs1 + ΣP2/Σs2
template <int KS>
__global__ __launch_bounds__(256) void k_combine(const __bf16* __restrict__ P1buf,
                                                 const float* __restrict__ S1buf,
                                                 const __bf16* __restrict__ P2buf,
                                                 const float* __restrict__ S2buf,
                                                 const float* __restrict__ gate,
                                                 __bf16* __restrict__ Ob) {
  const int idx = blockIdx.x * 256 + threadIdx.x;
  const int d = idx & 127;
  const int q = (idx >> 7) & 2047;
  const int h = idx >> 18;
  const size_t rq = (size_t)h * QLEN + q;
  float a1 = 0.f, a2 = 0.f, s1 = 0.f, s2 = 0.f;
#pragma unroll
  for (int zz = 0; zz < KS; ++zz) {
    const size_t zb = (size_t)zz * NH * QLEN;
    a1 += (float)P1buf[(zb + rq) * HD + d];
    a2 += (float)P2buf[(zb + rq) * HD + d];
    s1 += S1buf[zb + rq];
    s2 += S2buf[zb + rq];
  }
  float o = a1 * (gate[h] / s1) + a2 / s2;
  Ob[(size_t)q * DMODEL + h * HD + d] = (__bf16)o;
}

// ---------------- launch ----------------

extern "C" void kernel_launch(void* const* d_in, const int* in_sizes, int n_in,
                              void* d_out, int out_size, void* d_ws, size_t ws_size,
                              hipStream_t stream) {
  const float* x    = (const float*)d_in[0];
  const float* pk   = (const float*)d_in[1];
  const float* pv   = (const float*)d_in[2];
  const float* Wq   = (const float*)d_in[3];
  const float* bq   = (const float*)d_in[4];
  const float* Wk   = (const float*)d_in[5];
  const float* bk   = (const float*)d_in[6];
  const float* Wv   = (const float*)d_in[7];
  const float* bv   = (const float*)d_in[8];
  const float* gate = (const float*)d_in[9];
  const float* Wout = (const float*)d_in[10];
  const float* bout = (const float*)d_in[11];
  float* out = (float*)d_out;

  char* ws = (char*)d_ws;
  size_t off = 0;
  auto alc = [&](size_t bytes) -> char* {
    char* p = ws + off;
    off += bytes;
    off = (off + 255) & ~(size_t)255;
    return p;
  };
  __bf16* xb   = (__bf16*)alc((size_t)DMODEL * DMODEL * 2);
  __bf16* WqT  = (__bf16*)alc((size_t)DMODEL * DMODEL * 2);
  __bf16* WkT  = (__bf16*)alc((size_t)DMODEL * DMODEL * 2);
  __bf16* WvT  = (__bf16*)alc((size_t)DMODEL * DMODEL * 2);
  __bf16* WoT  = (__bf16*)alc((size_t)DMODEL * DMODEL * 2);
  __bf16* Qs   = (__bf16*)alc((size_t)NH * QLEN * HD * 2);
  __bf16* Kall = (__bf16*)alc((size_t)NH * KVLEN * HD * 2);
  __bf16* VTa  = (__bf16*)alc((size_t)NH * HD * KVLEN * 2);
  __bf16* Ob   = (__bf16*)alc((size_t)QLEN * DMODEL * 2);

  const size_t per_split = (size_t)NH * QLEN * HD * 2 * 2
                         + (size_t)NH * QLEN * 4 * 2 + 1024;
  int KS = (off + 2 * per_split <= ws_size) ? 2 : 1;
  __bf16* P1buf = (__bf16*)alc((size_t)KS * NH * QLEN * HD * 2);
  __bf16* P2buf = (__bf16*)alc((size_t)KS * NH * QLEN * HD * 2);
  float*  S1buf = (float*)alc((size_t)KS * NH * QLEN * 4);
  float*  S2buf = (float*)alc((size_t)KS * NH * QLEN * 4);

  k_prep<<<dim3(32, 32, 7), 256, 0, stream>>>(Wq, Wk, Wv, Wout, x, pk, pv,
                                              WqT, WkT, WvT, WoT, xb, Kall, VTa);

  gemm_qkv<<<dim3(16, 16, 3), 256, 0, stream>>>(xb, WqT, WkT, WvT, bq, bk, bv, Qs, Kall, VTa);

  const int ncomb = (NH * QLEN * HD) / 256;
  if (KS == 2) {
    k_attn<2><<<1024, 256, 0, stream>>>(Qs, Kall, VTa, P1buf, S1buf, P2buf, S2buf);
    k_combine<2><<<ncomb, 256, 0, stream>>>(P1buf, S1buf, P2buf, S2buf, gate, Ob);
  } else {
    k_attn<1><<<512, 256, 0, stream>>>(Qs, Kall, VTa, P1buf, S1buf, P2buf, S2buf);
    k_combine<1><<<ncomb, 256, 0, stream>>>(P1buf, S1buf, P2buf, S2buf, gate, Ob);
  }
  gemm_out<<<dim3(16, 32), 256, 0, stream>>>(Ob, WoT, bout, out);
}